// Round 7
// baseline (285.512 us; speedup 1.0000x reference)
//
#include <hip/hip_runtime.h>
#include <stdint.h>

// B=4, S=2048, D=1024, H=16, HD=64. All inputs fp32.
// convert->bf16; fused QKV GEMM (natural XCD map: XCD = blockIdx.x%8);
// flash attention (32x32 MFMA, swapped QK^T, all-register softmax with
// partial-max defer check + deferred sum reduce, shfl_xor(32) P half-swap,
// dbuf K/V, XCD swizzle) -> ao bf16; out = ao@wo^T+bo fp32.

#define B_ 4
#define S_ 2048
#define D_ 1024
#define H_ 16
#define HD_ 64
#define M_ (B_ * S_)

typedef __bf16 bf16x8 __attribute__((ext_vector_type(8)));
typedef float f32x4 __attribute__((ext_vector_type(4)));
typedef float f32x16 __attribute__((ext_vector_type(16)));
typedef unsigned short u16;

// 0.125 (1/sqrt(HD)) * log2(e): scores come out in log2 units
#define QSCALE 0.18033688011112042f
#define THR2 11.0f  // defer-max threshold in log2 units

__device__ __forceinline__ u16 f2bf(float f) {
  union { float f; unsigned u; } v; v.f = f;
  unsigned u = v.u;
  u += 0x7fff + ((u >> 16) & 1);
  return (u16)(u >> 16);
}

__device__ __forceinline__ float exp2_fast(float x) {
#if __has_builtin(__builtin_amdgcn_exp2f)
  return __builtin_amdgcn_exp2f(x);
#else
  return __expf(x * 0.69314718056f);
#endif
}

__device__ __forceinline__ unsigned packbf(float a, float b) {
  union { unsigned u; __bf16 h[2]; } v;
  v.h[0] = (__bf16)a; v.h[1] = (__bf16)b;
  return v.u;
}

__device__ __forceinline__ void gl2lds16(const void* g, void* l) {
  __builtin_amdgcn_global_load_lds(
      (const __attribute__((address_space(1))) unsigned int*)g,
      (__attribute__((address_space(3))) unsigned int*)l, 16, 0, 0);
}

// ---------------- convert fp32 -> bf16 ----------------
__global__ __launch_bounds__(256) void convert_kernel(
    const float* __restrict__ x, const float* __restrict__ wq,
    const float* __restrict__ wk, const float* __restrict__ wv,
    const float* __restrict__ wo, u16* __restrict__ xb, u16* __restrict__ wqb,
    u16* __restrict__ wkb, u16* __restrict__ wvb, u16* __restrict__ wob) {
  const int64_t NX = (int64_t)M_ * D_ / 4;
  const int64_t NW = (int64_t)D_ * D_ / 4;
  int64_t i = (int64_t)blockIdx.x * blockDim.x + threadIdx.x;
  const float* src; u16* dst; int64_t off;
  if (i < NX)              { src = x;  dst = xb;  off = i; }
  else if (i < NX + NW)    { src = wq; dst = wqb; off = i - NX; }
  else if (i < NX + 2*NW)  { src = wk; dst = wkb; off = i - NX - NW; }
  else if (i < NX + 3*NW)  { src = wv; dst = wvb; off = i - NX - 2*NW; }
  else                     { src = wo; dst = wob; off = i - NX - 3*NW; }
  float4 v = reinterpret_cast<const float4*>(src)[off];
  ushort4 o;
  o.x = f2bf(v.x); o.y = f2bf(v.y); o.z = f2bf(v.z); o.w = f2bf(v.w);
  reinterpret_cast<ushort4*>(dst)[off] = o;
}

// ---------------- fused QKV GEMM ----------------
// grid dim3(24, 64): x = widx*8 + cb (widx 0=Q,1=K,2=V), y = row-block.
// Linear id = x + 24*y -> XCD = x%8 (24 % 8 == 0): each XCD hosts 3 weight
// col-panels (0.75 MB, L2-resident), all row-blocks stream x.
// Q out scaled by QSCALE -> [B,H,S,HD]; K -> [B,H,S,HD]; V swapped -> V^T [B,H,HD,S].
__global__ __launch_bounds__(256) void gemm_qkv_kernel(
    const u16* __restrict__ A, const u16* __restrict__ wqb,
    const u16* __restrict__ wkb, const u16* __restrict__ wvb,
    const float* __restrict__ bq, const float* __restrict__ bk,
    const float* __restrict__ bv, u16* __restrict__ oq, u16* __restrict__ ok,
    u16* __restrict__ ovt) {
  __shared__ u16 As[128 * 64];
  __shared__ u16 Bs[128 * 64];
  const int widx = blockIdx.x >> 3;
  const int col0 = (blockIdx.x & 7) * 128;
  const int row0 = blockIdx.y * 128;
  const u16* Bw = (widx == 0) ? wqb : ((widx == 1) ? wkb : wvb);
  const float* bias = (widx == 0) ? bq : ((widx == 1) ? bk : bv);
  const int tid = threadIdx.x;
  const int lane = tid & 63;
  const int wid = tid >> 6;
  const int wr = (wid >> 1) * 64;
  const int wc = (wid & 1) * 64;

  f32x4 acc[4][4] = {};
  const int srow = lane >> 3;
  const int cc = (lane & 7) ^ srow;

  for (int kt = 0; kt < D_; kt += 64) {
    __syncthreads();
    for (int t = 0; t < 4; ++t) {
      int r = (wid * 4 + t) * 8 + srow;
      gl2lds16(A + (int64_t)(row0 + r) * D_ + kt + cc * 8,
               (char*)As + (wid * 4 + t) * 1024);
      gl2lds16(Bw + (int64_t)(col0 + r) * D_ + kt + cc * 8,
               (char*)Bs + (wid * 4 + t) * 1024);
    }
    __syncthreads();

    bf16x8 af[4][2], bfr[4][2];
#pragma unroll
    for (int mi = 0; mi < 4; ++mi)
#pragma unroll
      for (int ks = 0; ks < 2; ++ks) {
        int c = ks * 4 + (lane >> 4);
        int ra = wr + mi * 16 + (lane & 15);
        af[mi][ks] = *reinterpret_cast<const bf16x8*>(
            (char*)As + ra * 128 + ((c ^ (ra & 7)) << 4));
        int rb = wc + mi * 16 + (lane & 15);
        bfr[mi][ks] = *reinterpret_cast<const bf16x8*>(
            (char*)Bs + rb * 128 + ((c ^ (rb & 7)) << 4));
      }
    if (widx == 2) {
#pragma unroll
      for (int ks = 0; ks < 2; ++ks)
#pragma unroll
        for (int mi = 0; mi < 4; ++mi)
#pragma unroll
          for (int ni = 0; ni < 4; ++ni)
            acc[mi][ni] = __builtin_amdgcn_mfma_f32_16x16x32_bf16(
                bfr[ni][ks], af[mi][ks], acc[mi][ni], 0, 0, 0);
    } else {
#pragma unroll
      for (int ks = 0; ks < 2; ++ks)
#pragma unroll
        for (int mi = 0; mi < 4; ++mi)
#pragma unroll
          for (int ni = 0; ni < 4; ++ni)
            acc[mi][ni] = __builtin_amdgcn_mfma_f32_16x16x32_bf16(
                af[mi][ks], bfr[ni][ks], acc[mi][ni], 0, 0, 0);
    }
  }

  if (widx != 2) {
    u16* o = (widx == 0) ? oq : ok;
    const float sc = (widx == 0) ? QSCALE : 1.0f;
#pragma unroll
    for (int mi = 0; mi < 4; ++mi)
#pragma unroll
      for (int ni = 0; ni < 4; ++ni) {
        int j = col0 + wc + ni * 16 + (lane & 15);
        float bvv = bias[j];
        int h = j >> 6, hd = j & 63;
#pragma unroll
        for (int r = 0; r < 4; ++r) {
          int i = row0 + wr + mi * 16 + (lane >> 4) * 4 + r;
          int b = i >> 11, s = i & 2047;
          o[((int64_t)(b * H_ + h) * S_ + s) * HD_ + hd] =
              f2bf((acc[mi][ni][r] + bvv) * sc);
        }
      }
  } else {
#pragma unroll
    for (int mi = 0; mi < 4; ++mi)
#pragma unroll
      for (int ni = 0; ni < 4; ++ni) {
        int i = row0 + wr + mi * 16 + (lane & 15);
        int b = i >> 11, s = i & 2047;
#pragma unroll
        for (int r = 0; r < 4; ++r) {
          int j = col0 + wc + ni * 16 + (lane >> 4) * 4 + r;
          int h = j >> 6, hd = j & 63;
          ovt[((int64_t)(b * H_ + h) * HD_ + hd) * S_ + s] =
              f2bf(acc[mi][ni][r] + bias[j]);
        }
      }
  }
}

// ---------------- output projection GEMM (fp32 out) ----------------
// grid dim3(8,64): XCD = blockIdx.x -> wo col-panel (1MB) L2-resident per XCD.
__global__ __launch_bounds__(256) void gemm_out_kernel(
    const u16* __restrict__ A, const u16* __restrict__ Bw,
    const float* __restrict__ bias, float* __restrict__ out) {
  __shared__ u16 As[128 * 64];
  __shared__ u16 Bs[128 * 64];
  const int row0 = blockIdx.y * 128;
  const int col0 = blockIdx.x * 128;
  const int tid = threadIdx.x;
  const int lane = tid & 63;
  const int wid = tid >> 6;
  const int wr = (wid >> 1) * 64;
  const int wc = (wid & 1) * 64;

  f32x4 acc[4][4] = {};
  const int srow = lane >> 3;
  const int cc = (lane & 7) ^ srow;

  for (int kt = 0; kt < D_; kt += 64) {
    __syncthreads();
    for (int t = 0; t < 4; ++t) {
      int r = (wid * 4 + t) * 8 + srow;
      gl2lds16(A + (int64_t)(row0 + r) * D_ + kt + cc * 8,
               (char*)As + (wid * 4 + t) * 1024);
      gl2lds16(Bw + (int64_t)(col0 + r) * D_ + kt + cc * 8,
               (char*)Bs + (wid * 4 + t) * 1024);
    }
    __syncthreads();

    bf16x8 af[4][2], bfr[4][2];
#pragma unroll
    for (int mi = 0; mi < 4; ++mi)
#pragma unroll
      for (int ks = 0; ks < 2; ++ks) {
        int c = ks * 4 + (lane >> 4);
        int ra = wr + mi * 16 + (lane & 15);
        af[mi][ks] = *reinterpret_cast<const bf16x8*>(
            (char*)As + ra * 128 + ((c ^ (ra & 7)) << 4));
        int rb = wc + mi * 16 + (lane & 15);
        bfr[mi][ks] = *reinterpret_cast<const bf16x8*>(
            (char*)Bs + rb * 128 + ((c ^ (rb & 7)) << 4));
      }
#pragma unroll
    for (int ks = 0; ks < 2; ++ks)
#pragma unroll
      for (int mi = 0; mi < 4; ++mi)
#pragma unroll
        for (int ni = 0; ni < 4; ++ni)
          acc[mi][ni] = __builtin_amdgcn_mfma_f32_16x16x32_bf16(
              af[mi][ks], bfr[ni][ks], acc[mi][ni], 0, 0, 0);
  }

#pragma unroll
  for (int mi = 0; mi < 4; ++mi)
#pragma unroll
    for (int ni = 0; ni < 4; ++ni) {
      int j = col0 + wc + ni * 16 + (lane & 15);
      float bvv = bias[j];
#pragma unroll
      for (int r = 0; r < 4; ++r) {
        int i = row0 + wr + mi * 16 + (lane >> 4) * 4 + r;
        out[(int64_t)i * D_ + j] = acc[mi][ni][r] + bvv;
      }
    }
}

// ---------------- flash attention (32x32 MFMA, all-register softmax/P) ----------
// grid 1024 (XCD-swizzled), 4 waves; wave owns 32 q-rows. KV tiles of 64, dbuf.
// Swapped QK^T -> lane holds 64-kv slice of ONE q-row (split across lane/lane+32).
// Per-tile: NO cross-half shuffles (partial-max defer check, deferred sum reduce).
__global__ __launch_bounds__(256) void attn_kernel(
    const u16* __restrict__ Q, const u16* __restrict__ Kg,
    const u16* __restrict__ Vt, u16* __restrict__ AO) {
  __shared__ u16 Ks[2][64 * 64];   // swizzled [kv][hd]
  __shared__ u16 Vs[2][64 * 64];   // swizzled [hd][kv]
  const int tid = threadIdx.x;
  const int lane = tid & 63;
  const int l31 = lane & 31;
  const int hi = lane >> 5;
  const int wid = tid >> 6;
  const int orig = blockIdx.x;     // 1024
  const int swz = (orig & 7) * 128 + (orig >> 3);
  const int bh = swz >> 4;
  const int qw = (swz & 15) * 128 + wid * 32;

  // Q as B-operand (32x32x16): col q = l31, k = ks*16 + hi*8 + j
  bf16x8 qf[4];
#pragma unroll
  for (int ks = 0; ks < 4; ++ks)
    qf[ks] = *reinterpret_cast<const bf16x8*>(
        Q + ((int64_t)bh * S_ + qw + l31) * HD_ + ks * 16 + hi * 8);

  f32x16 o0 = {}, o1 = {};
  float mrow = -1e30f;
  float lrow = 0.f;  // PER-LANE PARTIAL (lane & lane+32 hold disjoint kv halves)

  const int srow = lane >> 3;
  const int cc = (lane & 7) ^ srow;

  // prologue: stage tile 0 -> buf 0
#pragma unroll
  for (int tt = 0; tt < 2; ++tt) {
    int r = (wid * 2 + tt) * 8 + srow;
    gl2lds16(Kg + ((int64_t)bh * S_ + r) * HD_ + cc * 8,
             (char*)Ks[0] + (wid * 2 + tt) * 1024);
    gl2lds16(Vt + ((int64_t)bh * HD_ + r) * S_ + cc * 8,
             (char*)Vs[0] + (wid * 2 + tt) * 1024);
  }

  const int NT = S_ / 64;
  for (int t = 0; t < NT; ++t) {
    const int cur = t & 1;
    asm volatile("s_waitcnt vmcnt(0)" ::: "memory");
    __builtin_amdgcn_s_barrier();
    if (t + 1 < NT) {
      int kv0 = (t + 1) * 64;
#pragma unroll
      for (int tt = 0; tt < 2; ++tt) {
        int r = (wid * 2 + tt) * 8 + srow;
        gl2lds16(Kg + ((int64_t)bh * S_ + kv0 + r) * HD_ + cc * 8,
                 (char*)Ks[cur ^ 1] + (wid * 2 + tt) * 1024);
        gl2lds16(Vt + ((int64_t)bh * HD_ + r) * S_ + kv0 + cc * 8,
                 (char*)Vs[cur ^ 1] + (wid * 2 + tt) * 1024);
      }
    }

    // QK^T: sc0 = kv 0..31, sc1 = kv 32..63 (C: col q=l31, row kv=(t&3)+8(t>>2)+4hi)
    f32x16 sc0 = {}, sc1 = {};
    {
      const char* kbase = (const char*)Ks[cur];
      __builtin_amdgcn_s_setprio(1);
#pragma unroll
      for (int ks = 0; ks < 4; ++ks) {
        int chunk = 2 * ks + hi;
        int r0 = l31, r1 = 32 + l31;
        bf16x8 k0 = *reinterpret_cast<const bf16x8*>(
            kbase + r0 * 128 + ((chunk ^ (r0 & 7)) << 4));
        bf16x8 k1 = *reinterpret_cast<const bf16x8*>(
            kbase + r1 * 128 + ((chunk ^ (r1 & 7)) << 4));
        sc0 = __builtin_amdgcn_mfma_f32_32x32x16_bf16(k0, qf[ks], sc0, 0, 0, 0);
        sc1 = __builtin_amdgcn_mfma_f32_32x32x16_bf16(k1, qf[ks], sc1, 0, 0, 0);
      }
      __builtin_amdgcn_s_setprio(0);
    }

    // PARTIAL max (this lane's 32 elems) — no cross-half shuffle needed:
    // __all over partial maxes == __all over row maxes (max decomposition).
    float a8[8];
#pragma unroll
    for (int i = 0; i < 8; ++i)
      a8[i] = fmaxf(fmaxf(fmaxf(sc0[2 * i], sc0[2 * i + 1]), sc1[2 * i]),
                    sc1[2 * i + 1]);
    float mx = fmaxf(fmaxf(fmaxf(fmaxf(a8[0], a8[1]), a8[2]), a8[3]),
                     fmaxf(fmaxf(fmaxf(a8[4], a8[5]), a8[6]), a8[7]));
    if (!__all((mx - mrow <= THR2) ? 1 : 0)) {  // rare rescale (always tile 0)
      float mxf = fmaxf(mx, __shfl_xor(mx, 32));  // row-true max, only here
      float mnew = fmaxf(mrow, mxf);
      float al = exp2_fast(mrow - mnew);
      mrow = mnew;
      lrow *= al;
#pragma unroll
      for (int tt = 0; tt < 16; ++tt) {
        float at = __shfl(al, (tt & 3) + 8 * (tt >> 2) + 4 * hi);
        o0[tt] *= at; o1[tt] *= at;
      }
    }
    // p = exp2(s - m); PARTIAL row sum accumulated per-lane (reduced at epilogue)
#pragma unroll
    for (int tt = 0; tt < 16; ++tt) {
      sc0[tt] = exp2_fast(sc0[tt] - mrow);
      sc1[tt] = exp2_fast(sc1[tt] - mrow);
    }
    float s8[8];
#pragma unroll
    for (int i = 0; i < 8; ++i)
      s8[i] = (sc0[2 * i] + sc0[2 * i + 1]) + (sc1[2 * i] + sc1[2 * i + 1]);
    lrow += ((s8[0] + s8[1]) + (s8[2] + s8[3])) +
            ((s8[4] + s8[5]) + (s8[6] + s8[7]));

    // pack P -> u32 words: w0/w1[rr][h] = bf16pair(kv = n2*32 + 8rr + 4hi + 2h +{0,1})
    unsigned w0[4][2], w1[4][2];
#pragma unroll
    for (int rr = 0; rr < 4; ++rr)
#pragma unroll
      for (int h2 = 0; h2 < 2; ++h2) {
        w0[rr][h2] = packbf(sc0[4 * rr + 2 * h2], sc0[4 * rr + 2 * h2 + 1]);
        w1[rr][h2] = packbf(sc1[4 * rr + 2 * h2], sc1[4 * rr + 2 * h2 + 1]);
      }
    // half-swap: hi=0 sends odd-rr words, hi=1 sends even-rr words
    unsigned rv0[2][2], rv1[2][2];
#pragma unroll
    for (int c = 0; c < 2; ++c)
#pragma unroll
      for (int h2 = 0; h2 < 2; ++h2) {
        rv0[c][h2] = (unsigned)__shfl_xor(
            (int)(hi ? w0[2 * c][h2] : w0[2 * c + 1][h2]), 32);
        rv1[c][h2] = (unsigned)__shfl_xor(
            (int)(hi ? w1[2 * c][h2] : w1[2 * c + 1][h2]), 32);
      }

    // PV: o[q][hd] += P[q][kv] * V[kv][hd]; A-frag kb covers kv = kb*16 + hi*8 + j
    {
      const char* vbase = (const char*)Vs[cur];
      __builtin_amdgcn_s_setprio(1);
#pragma unroll
      for (int kb = 0; kb < 4; ++kb) {
        const int c = kb & 1;
        union { bf16x8 v; unsigned u[4]; } pu;
        if (kb < 2) {
          pu.u[0] = hi ? rv0[c][0] : w0[2 * c][0];
          pu.u[1] = hi ? rv0[c][1] : w0[2 * c][1];
          pu.u[2] = hi ? w0[2 * c + 1][0] : rv0[c][0];
          pu.u[3] = hi ? w0[2 * c + 1][1] : rv0[c][1];
        } else {
          pu.u[0] = hi ? rv1[c][0] : w1[2 * c][0];
          pu.u[1] = hi ? rv1[c][1] : w1[2 * c][1];
          pu.u[2] = hi ? w1[2 * c + 1][0] : rv1[c][0];
          pu.u[3] = hi ? w1[2 * c + 1][1] : rv1[c][1];
        }
        int chunk = 2 * kb + hi;
        int r0 = l31, r1 = 32 + l31;
        bf16x8 v0 = *reinterpret_cast<const bf16x8*>(
            vbase + r0 * 128 + ((chunk ^ (r0 & 7)) << 4));
        bf16x8 v1 = *reinterpret_cast<const bf16x8*>(
            vbase + r1 * 128 + ((chunk ^ (r1 & 7)) << 4));
        o0 = __builtin_amdgcn_mfma_f32_32x32x16_bf16(pu.v, v0, o0, 0, 0, 0);
        o1 = __builtin_amdgcn_mfma_f32_32x32x16_bf16(pu.v, v1, o1, 0, 0, 0);
      }
      __builtin_amdgcn_s_setprio(0);
    }
  }

  // epilogue: ONE cross-half sum reduce, normalize, store.
  lrow += __shfl_xor(lrow, 32);
  const int b = bh >> 4, h = bh & 15;
  float linv = __builtin_amdgcn_rcpf(lrow);
#pragma unroll
  for (int tt = 0; tt < 16; ++tt) {
    int row = (tt & 3) + 8 * (tt >> 2) + 4 * hi;
    float inv = __shfl(linv, row);
    int qr = qw + row;
    int64_t base = ((int64_t)(b * S_ + qr)) * D_ + h * HD_ + l31;
    AO[base] = f2bf(o0[tt] * inv);
    AO[base + 32] = f2bf(o1[tt] * inv);
  }
}

extern "C" void kernel_launch(void* const* d_in, const int* in_sizes, int n_in,
                              void* d_out, int out_size, void* d_ws, size_t ws_size,
                              hipStream_t stream) {
  const float* x  = (const float*)d_in[0];
  const float* wq = (const float*)d_in[1];
  const float* bq = (const float*)d_in[2];
  const float* wk = (const float*)d_in[3];
  const float* bk = (const float*)d_in[4];
  const float* wv = (const float*)d_in[5];
  const float* bv = (const float*)d_in[6];
  const float* wo = (const float*)d_in[7];
  const float* bo = (const float*)d_in[8];
  char* ws = (char*)d_ws;
  u16* xb  = (u16*)ws;
  u16* wqb = (u16*)(ws + (16ll << 20));
  u16* wkb = (u16*)(ws + (18ll << 20));
  u16* wvb = (u16*)(ws + (20ll << 20));
  u16* wob = (u16*)(ws + (22ll << 20));
  u16* q   = (u16*)(ws + (24ll << 20));
  u16* k   = (u16*)(ws + (40ll << 20));
  u16* vt  = (u16*)(ws + (56ll << 20));
  u16* ao  = xb;

  convert_kernel<<<12288, 256, 0, stream>>>(x, wq, wk, wv, wo, xb, wqb, wkb, wvb, wob);
  gemm_qkv_kernel<<<dim3(24, 64), 256, 0, stream>>>(xb, wqb, wkb, wvb, bq, bk, bv,
                                                    q, k, vt);
  attn_kernel<<<1024, 256, 0, stream>>>(q, k, vt, ao);
  gemm_out_kernel<<<dim3(8, 64), 256, 0, stream>>>(ao, wob, bo, (float*)d_out);
}

// Round 8
// 249.910 us; speedup vs baseline: 1.1425x; 1.1425x over previous
//
#include <hip/hip_runtime.h>
#include <stdint.h>

// B=4, S=2048, D=1024, H=16, HD=64. All inputs fp32.
// convert->bf16; Q(pre-scaled by 0.125*log2e),K in [B,H,S,HD]; V^T [B,H,HD,S];
// flash attention (32x32 MFMA, swapped QK^T, register softmax with partial-max
// defer check, MFMA-computed denominator l = P@1, shfl_xor(32) P half-swap,
// x2-unrolled tile loop, dbuf K/V, XCD swizzle) -> ao bf16; out = ao@wo^T+bo fp32.

#define B_ 4
#define S_ 2048
#define D_ 1024
#define H_ 16
#define HD_ 64
#define M_ (B_ * S_)

typedef __bf16 bf16x8 __attribute__((ext_vector_type(8)));
typedef float f32x4 __attribute__((ext_vector_type(4)));
typedef float f32x16 __attribute__((ext_vector_type(16)));
typedef unsigned short u16;

// 0.125 (1/sqrt(HD)) * log2(e): scores come out in log2 units
#define QSCALE 0.18033688011112042f
#define THR2 11.0f  // defer-max threshold in log2 units

__device__ __forceinline__ u16 f2bf(float f) {
  union { float f; unsigned u; } v; v.f = f;
  unsigned u = v.u;
  u += 0x7fff + ((u >> 16) & 1);
  return (u16)(u >> 16);
}

__device__ __forceinline__ float exp2_fast(float x) {
#if __has_builtin(__builtin_amdgcn_exp2f)
  return __builtin_amdgcn_exp2f(x);
#else
  return __expf(x * 0.69314718056f);
#endif
}

__device__ __forceinline__ unsigned packbf(float a, float b) {
  union { unsigned u; __bf16 h[2]; } v;
  v.h[0] = (__bf16)a; v.h[1] = (__bf16)b;
  return v.u;
}

__device__ __forceinline__ void gl2lds16(const void* g, void* l) {
  __builtin_amdgcn_global_load_lds(
      (const __attribute__((address_space(1))) unsigned int*)g,
      (__attribute__((address_space(3))) unsigned int*)l, 16, 0, 0);
}

// ---------------- convert fp32 -> bf16 ----------------
__global__ __launch_bounds__(256) void convert_kernel(
    const float* __restrict__ x, const float* __restrict__ wq,
    const float* __restrict__ wk, const float* __restrict__ wv,
    const float* __restrict__ wo, u16* __restrict__ xb, u16* __restrict__ wqb,
    u16* __restrict__ wkb, u16* __restrict__ wvb, u16* __restrict__ wob) {
  const int64_t NX = (int64_t)M_ * D_ / 4;
  const int64_t NW = (int64_t)D_ * D_ / 4;
  int64_t i = (int64_t)blockIdx.x * blockDim.x + threadIdx.x;
  const float* src; u16* dst; int64_t off;
  if (i < NX)              { src = x;  dst = xb;  off = i; }
  else if (i < NX + NW)    { src = wq; dst = wqb; off = i - NX; }
  else if (i < NX + 2*NW)  { src = wk; dst = wkb; off = i - NX - NW; }
  else if (i < NX + 3*NW)  { src = wv; dst = wvb; off = i - NX - 2*NW; }
  else                     { src = wo; dst = wob; off = i - NX - 3*NW; }
  float4 v = reinterpret_cast<const float4*>(src)[off];
  ushort4 o;
  o.x = f2bf(v.x); o.y = f2bf(v.y); o.z = f2bf(v.z); o.w = f2bf(v.w);
  reinterpret_cast<ushort4*>(dst)[off] = o;
}

// ---------------- bf16 MFMA GEMM: C = A(MxK) @ Bw(NxK)^T + bias ----------------
// MODE 0: bf16 out [B,H,S,HD] (K proj)   MODE 3: same, scaled by QSCALE (Q proj)
// MODE 1: swapped, bf16 out [B,H,HD,S] (V^T)   MODE 2: fp32 out [M,N] (final)
template <int MODE>
__global__ __launch_bounds__(256) void gemm_kernel(
    const u16* __restrict__ A, const u16* __restrict__ Bw,
    const float* __restrict__ bias, void* __restrict__ out) {
  __shared__ u16 As[128 * 64];
  __shared__ u16 Bs[128 * 64];
  const int tid = threadIdx.x;
  const int lane = tid & 63;
  const int wid = tid >> 6;
  const int row0 = blockIdx.y * 128;
  const int col0 = blockIdx.x * 128;
  const int wr = (wid >> 1) * 64;
  const int wc = (wid & 1) * 64;

  f32x4 acc[4][4] = {};
  const int srow = lane >> 3;
  const int cc = (lane & 7) ^ srow;

  for (int kt = 0; kt < D_; kt += 64) {
    __syncthreads();
    for (int t = 0; t < 4; ++t) {
      int r = (wid * 4 + t) * 8 + srow;
      gl2lds16(A + (int64_t)(row0 + r) * D_ + kt + cc * 8,
               (char*)As + (wid * 4 + t) * 1024);
      gl2lds16(Bw + (int64_t)(col0 + r) * D_ + kt + cc * 8,
               (char*)Bs + (wid * 4 + t) * 1024);
    }
    __syncthreads();

    bf16x8 af[4][2], bfr[4][2];
#pragma unroll
    for (int mi = 0; mi < 4; ++mi)
#pragma unroll
      for (int ks = 0; ks < 2; ++ks) {
        int c = ks * 4 + (lane >> 4);
        int ra = wr + mi * 16 + (lane & 15);
        af[mi][ks] = *reinterpret_cast<const bf16x8*>(
            (char*)As + ra * 128 + ((c ^ (ra & 7)) << 4));
        int rb = wc + mi * 16 + (lane & 15);
        bfr[mi][ks] = *reinterpret_cast<const bf16x8*>(
            (char*)Bs + rb * 128 + ((c ^ (rb & 7)) << 4));
      }
#pragma unroll
    for (int ks = 0; ks < 2; ++ks)
#pragma unroll
      for (int mi = 0; mi < 4; ++mi)
#pragma unroll
        for (int ni = 0; ni < 4; ++ni) {
          if (MODE == 1)
            acc[mi][ni] = __builtin_amdgcn_mfma_f32_16x16x32_bf16(
                bfr[ni][ks], af[mi][ks], acc[mi][ni], 0, 0, 0);
          else
            acc[mi][ni] = __builtin_amdgcn_mfma_f32_16x16x32_bf16(
                af[mi][ks], bfr[ni][ks], acc[mi][ni], 0, 0, 0);
        }
  }

  if (MODE == 0 || MODE == 3) {
    u16* o = (u16*)out;
#pragma unroll
    for (int mi = 0; mi < 4; ++mi)
#pragma unroll
      for (int ni = 0; ni < 4; ++ni) {
        int j = col0 + wc + ni * 16 + (lane & 15);
        float bvv = bias[j];
        int h = j >> 6, hd = j & 63;
#pragma unroll
        for (int r = 0; r < 4; ++r) {
          int i = row0 + wr + mi * 16 + (lane >> 4) * 4 + r;
          int b = i >> 11, s = i & 2047;
          float val = acc[mi][ni][r] + bvv;
          if (MODE == 3) val *= QSCALE;
          o[((int64_t)(b * H_ + h) * S_ + s) * HD_ + hd] = f2bf(val);
        }
      }
  } else if (MODE == 1) {
    u16* o = (u16*)out;
#pragma unroll
    for (int mi = 0; mi < 4; ++mi)
#pragma unroll
      for (int ni = 0; ni < 4; ++ni) {
        int i = row0 + wr + mi * 16 + (lane & 15);
        int b = i >> 11, s = i & 2047;
#pragma unroll
        for (int r = 0; r < 4; ++r) {
          int j = col0 + wc + ni * 16 + (lane >> 4) * 4 + r;
          int h = j >> 6, hd = j & 63;
          o[((int64_t)(b * H_ + h) * HD_ + hd) * S_ + s] = f2bf(acc[mi][ni][r] + bias[j]);
        }
      }
  } else {
    float* o = (float*)out;
#pragma unroll
    for (int mi = 0; mi < 4; ++mi)
#pragma unroll
      for (int ni = 0; ni < 4; ++ni) {
        int j = col0 + wc + ni * 16 + (lane & 15);
        float bvv = bias[j];
#pragma unroll
        for (int r = 0; r < 4; ++r) {
          int i = row0 + wr + mi * 16 + (lane >> 4) * 4 + r;
          o[(int64_t)i * D_ + j] = acc[mi][ni][r] + bvv;
        }
      }
  }
}

// ---------------- flash attention (32x32 MFMA, MFMA-denominator) ----------------
// grid 1024 (XCD-swizzled), 4 waves; wave owns 32 q-rows. KV tiles of 64, dbuf.
// Swapped QK^T -> lane (l31,hi) holds q-row l31's kv-slice. l = P@ones via MFMA
// (lands in o0's reg layout -> elementwise epilogue, no shuffles).
__global__ __launch_bounds__(256) void attn_kernel(
    const u16* __restrict__ Q, const u16* __restrict__ Kg,
    const u16* __restrict__ Vt, u16* __restrict__ AO) {
  __shared__ u16 Ks[2][64 * 64];   // swizzled [kv][hd]
  __shared__ u16 Vs[2][64 * 64];   // swizzled [hd][kv]
  const int tid = threadIdx.x;
  const int lane = tid & 63;
  const int l31 = lane & 31;
  const int hi = lane >> 5;
  const int wid = tid >> 6;
  const int orig = blockIdx.x;     // 1024
  const int swz = (orig & 7) * 128 + (orig >> 3);
  const int bh = swz >> 4;
  const int qw = (swz & 15) * 128 + wid * 32;

  // Q as B-operand (32x32x16): col q = l31, k = ks*16 + hi*8 + j
  bf16x8 qf[4];
#pragma unroll
  for (int ks = 0; ks < 4; ++ks)
    qf[ks] = *reinterpret_cast<const bf16x8*>(
        Q + ((int64_t)bh * S_ + qw + l31) * HD_ + ks * 16 + hi * 8);

  bf16x8 ones8;
#pragma unroll
  for (int i = 0; i < 8; ++i) ones8[i] = (__bf16)1.0f;

  f32x16 o0 = {}, o1 = {}, ls = {};
  float mrow = -1e30f;

  const int srow = lane >> 3;
  const int cc = (lane & 7) ^ srow;

  // staging pointers (per-lane, advanced each tile)
  const u16* kp0 = Kg + ((int64_t)bh * S_ + (wid * 2 + 0) * 8 + srow) * HD_ + cc * 8;
  const u16* kp1 = Kg + ((int64_t)bh * S_ + (wid * 2 + 1) * 8 + srow) * HD_ + cc * 8;
  const u16* vp0 = Vt + ((int64_t)bh * HD_ + (wid * 2 + 0) * 8 + srow) * S_ + cc * 8;
  const u16* vp1 = Vt + ((int64_t)bh * HD_ + (wid * 2 + 1) * 8 + srow) * S_ + cc * 8;

  // prologue: stage tile 0 -> buf 0
  gl2lds16(kp0, (char*)Ks[0] + (wid * 2 + 0) * 1024); kp0 += 64 * HD_;
  gl2lds16(kp1, (char*)Ks[0] + (wid * 2 + 1) * 1024); kp1 += 64 * HD_;
  gl2lds16(vp0, (char*)Vs[0] + (wid * 2 + 0) * 1024); vp0 += 64;
  gl2lds16(vp1, (char*)Vs[0] + (wid * 2 + 1) * 1024); vp1 += 64;

  const int NT = S_ / 64;

#define TILE_STEP(T, CUR)                                                      \
  {                                                                            \
    asm volatile("s_waitcnt vmcnt(0)" ::: "memory");                           \
    __builtin_amdgcn_s_barrier();                                              \
    if ((T) + 1 < NT) {                                                        \
      gl2lds16(kp0, (char*)Ks[(CUR) ^ 1] + (wid * 2 + 0) * 1024);              \
      gl2lds16(kp1, (char*)Ks[(CUR) ^ 1] + (wid * 2 + 1) * 1024);              \
      gl2lds16(vp0, (char*)Vs[(CUR) ^ 1] + (wid * 2 + 0) * 1024);              \
      gl2lds16(vp1, (char*)Vs[(CUR) ^ 1] + (wid * 2 + 1) * 1024);              \
      kp0 += 64 * HD_; kp1 += 64 * HD_; vp0 += 64; vp1 += 64;                  \
    }                                                                          \
    f32x16 sc0 = {}, sc1 = {};                                                 \
    {                                                                          \
      const char* kbase = (const char*)Ks[CUR];                                \
      __builtin_amdgcn_s_setprio(1);                                           \
      _Pragma("unroll")                                                        \
      for (int ks = 0; ks < 4; ++ks) {                                         \
        int chunk = 2 * ks + hi;                                               \
        int r0 = l31, r1 = 32 + l31;                                           \
        bf16x8 k0 = *reinterpret_cast<const bf16x8*>(                          \
            kbase + r0 * 128 + ((chunk ^ (r0 & 7)) << 4));                     \
        bf16x8 k1 = *reinterpret_cast<const bf16x8*>(                          \
            kbase + r1 * 128 + ((chunk ^ (r1 & 7)) << 4));                     \
        sc0 = __builtin_amdgcn_mfma_f32_32x32x16_bf16(k0, qf[ks], sc0, 0, 0, 0); \
        sc1 = __builtin_amdgcn_mfma_f32_32x32x16_bf16(k1, qf[ks], sc1, 0, 0, 0); \
      }                                                                        \
      __builtin_amdgcn_s_setprio(0);                                           \
    }                                                                          \
    float a8[8];                                                               \
    _Pragma("unroll")                                                          \
    for (int i = 0; i < 8; ++i)                                                \
      a8[i] = fmaxf(fmaxf(fmaxf(sc0[2 * i], sc0[2 * i + 1]), sc1[2 * i]),      \
                    sc1[2 * i + 1]);                                           \
    float mx = fmaxf(fmaxf(fmaxf(fmaxf(a8[0], a8[1]), a8[2]), a8[3]),          \
                     fmaxf(fmaxf(fmaxf(a8[4], a8[5]), a8[6]), a8[7]));         \
    if (!__all((mx - mrow <= THR2) ? 1 : 0)) {                                 \
      float mxf = fmaxf(mx, __shfl_xor(mx, 32));                               \
      float mnew = fmaxf(mrow, mxf);                                           \
      float al = exp2_fast(mrow - mnew);                                       \
      mrow = mnew;                                                             \
      _Pragma("unroll")                                                        \
      for (int tt = 0; tt < 16; ++tt) {                                        \
        float at = __shfl(al, (tt & 3) + 8 * (tt >> 2) + 4 * hi);              \
        o0[tt] *= at; o1[tt] *= at; ls[tt] *= at;                              \
      }                                                                        \
    }                                                                          \
    _Pragma("unroll")                                                          \
    for (int tt = 0; tt < 16; ++tt) {                                          \
      sc0[tt] = exp2_fast(sc0[tt] - mrow);                                     \
      sc1[tt] = exp2_fast(sc1[tt] - mrow);                                     \
    }                                                                          \
    unsigned w0[4][2], w1[4][2];                                               \
    _Pragma("unroll")                                                          \
    for (int rr = 0; rr < 4; ++rr) {                                           \
      w0[rr][0] = packbf(sc0[4 * rr], sc0[4 * rr + 1]);                        \
      w0[rr][1] = packbf(sc0[4 * rr + 2], sc0[4 * rr + 3]);                    \
      w1[rr][0] = packbf(sc1[4 * rr], sc1[4 * rr + 1]);                        \
      w1[rr][1] = packbf(sc1[4 * rr + 2], sc1[4 * rr + 3]);                    \
    }                                                                          \
    unsigned rv0[2][2], rv1[2][2];                                             \
    _Pragma("unroll")                                                          \
    for (int c = 0; c < 2; ++c) {                                              \
      _Pragma("unroll")                                                        \
      for (int h2 = 0; h2 < 2; ++h2) {                                         \
        rv0[c][h2] = (unsigned)__shfl_xor(                                     \
            (int)(hi ? w0[2 * c][h2] : w0[2 * c + 1][h2]), 32);                \
        rv1[c][h2] = (unsigned)__shfl_xor(                                     \
            (int)(hi ? w1[2 * c][h2] : w1[2 * c + 1][h2]), 32);                \
      }                                                                        \
    }                                                                          \
    {                                                                          \
      const char* vbase = (const char*)Vs[CUR];                                \
      __builtin_amdgcn_s_setprio(1);                                           \
      _Pragma("unroll")                                                        \
      for (int kb = 0; kb < 4; ++kb) {                                         \
        const int c = kb & 1;                                                  \
        union { bf16x8 v; unsigned u[4]; } pu;                                 \
        if (kb < 2) {                                                          \
          pu.u[0] = hi ? rv0[c][0] : w0[2 * c][0];                             \
          pu.u[1] = hi ? rv0[c][1] : w0[2 * c][1];                             \
          pu.u[2] = hi ? w0[2 * c + 1][0] : rv0[c][0];                         \
          pu.u[3] = hi ? w0[2 * c + 1][1] : rv0[c][1];                         \
        } else {                                                               \
          pu.u[0] = hi ? rv1[c][0] : w1[2 * c][0];                             \
          pu.u[1] = hi ? rv1[c][1] : w1[2 * c][1];                             \
          pu.u[2] = hi ? w1[2 * c + 1][0] : rv1[c][0];                         \
          pu.u[3] = hi ? w1[2 * c + 1][1] : rv1[c][1];                         \
        }                                                                      \
        int chunk = 2 * kb + hi;                                               \
        int r0 = l31, r1 = 32 + l31;                                           \
        bf16x8 v0 = *reinterpret_cast<const bf16x8*>(                          \
            vbase + r0 * 128 + ((chunk ^ (r0 & 7)) << 4));                     \
        bf16x8 v1 = *reinterpret_cast<const bf16x8*>(                          \
            vbase + r1 * 128 + ((chunk ^ (r1 & 7)) << 4));                     \
        o0 = __builtin_amdgcn_mfma_f32_32x32x16_bf16(pu.v, v0, o0, 0, 0, 0);   \
        o1 = __builtin_amdgcn_mfma_f32_32x32x16_bf16(pu.v, v1, o1, 0, 0, 0);   \
        ls = __builtin_amdgcn_mfma_f32_32x32x16_bf16(pu.v, ones8, ls, 0, 0, 0);\
      }                                                                        \
      __builtin_amdgcn_s_setprio(0);                                           \
    }                                                                          \
  }

  for (int t = 0; t < NT; t += 2) {
    TILE_STEP(t, 0)
    TILE_STEP(t + 1, 1)
  }
#undef TILE_STEP

  // epilogue: elementwise normalize (ls has o0's exact layout), store
  const int b = bh >> 4, h = bh & 15;
#pragma unroll
  for (int tt = 0; tt < 16; ++tt) {
    int row = (tt & 3) + 8 * (tt >> 2) + 4 * hi;
    float inv = __builtin_amdgcn_rcpf(ls[tt]);
    int qr = qw + row;
    int64_t base = ((int64_t)(b * S_ + qr)) * D_ + h * HD_ + l31;
    AO[base] = f2bf(o0[tt] * inv);
    AO[base + 32] = f2bf(o1[tt] * inv);
  }
}

extern "C" void kernel_launch(void* const* d_in, const int* in_sizes, int n_in,
                              void* d_out, int out_size, void* d_ws, size_t ws_size,
                              hipStream_t stream) {
  const float* x  = (const float*)d_in[0];
  const float* wq = (const float*)d_in[1];
  const float* bq = (const float*)d_in[2];
  const float* wk = (const float*)d_in[3];
  const float* bk = (const float*)d_in[4];
  const float* wv = (const float*)d_in[5];
  const float* bv = (const float*)d_in[6];
  const float* wo = (const float*)d_in[7];
  const float* bo = (const float*)d_in[8];
  char* ws = (char*)d_ws;
  u16* xb  = (u16*)ws;
  u16* wqb = (u16*)(ws + (16ll << 20));
  u16* wkb = (u16*)(ws + (18ll << 20));
  u16* wvb = (u16*)(ws + (20ll << 20));
  u16* wob = (u16*)(ws + (22ll << 20));
  u16* q   = (u16*)(ws + (24ll << 20));
  u16* k   = (u16*)(ws + (40ll << 20));
  u16* vt  = (u16*)(ws + (56ll << 20));
  u16* ao  = xb;

  convert_kernel<<<12288, 256, 0, stream>>>(x, wq, wk, wv, wo, xb, wqb, wkb, wvb, wob);
  dim3 gg(D_ / 128, M_ / 128);  // natural map: XCD = col-block (weight panel resident)
  gemm_kernel<3><<<gg, 256, 0, stream>>>(xb, wqb, bq, q);   // Q, pre-scaled
  gemm_kernel<0><<<gg, 256, 0, stream>>>(xb, wkb, bk, k);
  gemm_kernel<1><<<gg, 256, 0, stream>>>(xb, wvb, bv, vt);  // V^T
  attn_kernel<<<1024, 256, 0, stream>>>(q, k, vt, ao);
  gemm_kernel<2><<<gg, 256, 0, stream>>>(ao, wob, bo, (float*)d_out);
}

// Round 9
// 245.308 us; speedup vs baseline: 1.1639x; 1.0188x over previous
//
#include <hip/hip_runtime.h>
#include <stdint.h>

// B=4, S=2048, D=1024, H=16, HD=64. All inputs fp32.
// convert->bf16; Q(pre-scaled by 0.125*log2e),K in [B,H,S,HD]; V^T [B,H,HD,S];
// flash attention (8-wave blocks: 256 q-rows share each staged KV tile; 32x32
// MFMA, swapped QK^T, register softmax, MFMA denominator, shfl_xor(32) P swap,
// dbuf K/V, XCD swizzle) -> ao bf16; out = ao@wo^T+bo fp32.

#define B_ 4
#define S_ 2048
#define D_ 1024
#define H_ 16
#define HD_ 64
#define M_ (B_ * S_)

typedef __bf16 bf16x8 __attribute__((ext_vector_type(8)));
typedef float f32x4 __attribute__((ext_vector_type(4)));
typedef float f32x16 __attribute__((ext_vector_type(16)));
typedef unsigned short u16;

// 0.125 (1/sqrt(HD)) * log2(e): scores come out in log2 units
#define QSCALE 0.18033688011112042f
#define THR2 11.0f  // defer-max threshold in log2 units

__device__ __forceinline__ u16 f2bf(float f) {
  union { float f; unsigned u; } v; v.f = f;
  unsigned u = v.u;
  u += 0x7fff + ((u >> 16) & 1);
  return (u16)(u >> 16);
}

__device__ __forceinline__ float exp2_fast(float x) {
#if __has_builtin(__builtin_amdgcn_exp2f)
  return __builtin_amdgcn_exp2f(x);
#else
  return __expf(x * 0.69314718056f);
#endif
}

__device__ __forceinline__ unsigned packbf(float a, float b) {
  union { unsigned u; __bf16 h[2]; } v;
  v.h[0] = (__bf16)a; v.h[1] = (__bf16)b;
  return v.u;
}

__device__ __forceinline__ void gl2lds16(const void* g, void* l) {
  __builtin_amdgcn_global_load_lds(
      (const __attribute__((address_space(1))) unsigned int*)g,
      (__attribute__((address_space(3))) unsigned int*)l, 16, 0, 0);
}

// ---------------- convert fp32 -> bf16 ----------------
__global__ __launch_bounds__(256) void convert_kernel(
    const float* __restrict__ x, const float* __restrict__ wq,
    const float* __restrict__ wk, const float* __restrict__ wv,
    const float* __restrict__ wo, u16* __restrict__ xb, u16* __restrict__ wqb,
    u16* __restrict__ wkb, u16* __restrict__ wvb, u16* __restrict__ wob) {
  const int64_t NX = (int64_t)M_ * D_ / 4;
  const int64_t NW = (int64_t)D_ * D_ / 4;
  int64_t i = (int64_t)blockIdx.x * blockDim.x + threadIdx.x;
  const float* src; u16* dst; int64_t off;
  if (i < NX)              { src = x;  dst = xb;  off = i; }
  else if (i < NX + NW)    { src = wq; dst = wqb; off = i - NX; }
  else if (i < NX + 2*NW)  { src = wk; dst = wkb; off = i - NX - NW; }
  else if (i < NX + 3*NW)  { src = wv; dst = wvb; off = i - NX - 2*NW; }
  else                     { src = wo; dst = wob; off = i - NX - 3*NW; }
  float4 v = reinterpret_cast<const float4*>(src)[off];
  ushort4 o;
  o.x = f2bf(v.x); o.y = f2bf(v.y); o.z = f2bf(v.z); o.w = f2bf(v.w);
  reinterpret_cast<ushort4*>(dst)[off] = o;
}

// ---------------- bf16 MFMA GEMM: C = A(MxK) @ Bw(NxK)^T + bias ----------------
// MODE 0: bf16 out [B,H,S,HD] (K proj)   MODE 3: same, scaled by QSCALE (Q proj)
// MODE 1: swapped, bf16 out [B,H,HD,S] (V^T)   MODE 2: fp32 out [M,N] (final)
template <int MODE>
__global__ __launch_bounds__(256) void gemm_kernel(
    const u16* __restrict__ A, const u16* __restrict__ Bw,
    const float* __restrict__ bias, void* __restrict__ out) {
  __shared__ u16 As[128 * 64];
  __shared__ u16 Bs[128 * 64];
  const int tid = threadIdx.x;
  const int lane = tid & 63;
  const int wid = tid >> 6;
  const int row0 = blockIdx.y * 128;
  const int col0 = blockIdx.x * 128;
  const int wr = (wid >> 1) * 64;
  const int wc = (wid & 1) * 64;

  f32x4 acc[4][4] = {};
  const int srow = lane >> 3;
  const int cc = (lane & 7) ^ srow;

  for (int kt = 0; kt < D_; kt += 64) {
    __syncthreads();
    for (int t = 0; t < 4; ++t) {
      int r = (wid * 4 + t) * 8 + srow;
      gl2lds16(A + (int64_t)(row0 + r) * D_ + kt + cc * 8,
               (char*)As + (wid * 4 + t) * 1024);
      gl2lds16(Bw + (int64_t)(col0 + r) * D_ + kt + cc * 8,
               (char*)Bs + (wid * 4 + t) * 1024);
    }
    __syncthreads();

    bf16x8 af[4][2], bfr[4][2];
#pragma unroll
    for (int mi = 0; mi < 4; ++mi)
#pragma unroll
      for (int ks = 0; ks < 2; ++ks) {
        int c = ks * 4 + (lane >> 4);
        int ra = wr + mi * 16 + (lane & 15);
        af[mi][ks] = *reinterpret_cast<const bf16x8*>(
            (char*)As + ra * 128 + ((c ^ (ra & 7)) << 4));
        int rb = wc + mi * 16 + (lane & 15);
        bfr[mi][ks] = *reinterpret_cast<const bf16x8*>(
            (char*)Bs + rb * 128 + ((c ^ (rb & 7)) << 4));
      }
#pragma unroll
    for (int ks = 0; ks < 2; ++ks)
#pragma unroll
      for (int mi = 0; mi < 4; ++mi)
#pragma unroll
        for (int ni = 0; ni < 4; ++ni) {
          if (MODE == 1)
            acc[mi][ni] = __builtin_amdgcn_mfma_f32_16x16x32_bf16(
                bfr[ni][ks], af[mi][ks], acc[mi][ni], 0, 0, 0);
          else
            acc[mi][ni] = __builtin_amdgcn_mfma_f32_16x16x32_bf16(
                af[mi][ks], bfr[ni][ks], acc[mi][ni], 0, 0, 0);
        }
  }

  if (MODE == 0 || MODE == 3) {
    u16* o = (u16*)out;
#pragma unroll
    for (int mi = 0; mi < 4; ++mi)
#pragma unroll
      for (int ni = 0; ni < 4; ++ni) {
        int j = col0 + wc + ni * 16 + (lane & 15);
        float bvv = bias[j];
        int h = j >> 6, hd = j & 63;
#pragma unroll
        for (int r = 0; r < 4; ++r) {
          int i = row0 + wr + mi * 16 + (lane >> 4) * 4 + r;
          int b = i >> 11, s = i & 2047;
          float val = acc[mi][ni][r] + bvv;
          if (MODE == 3) val *= QSCALE;
          o[((int64_t)(b * H_ + h) * S_ + s) * HD_ + hd] = f2bf(val);
        }
      }
  } else if (MODE == 1) {
    u16* o = (u16*)out;
#pragma unroll
    for (int mi = 0; mi < 4; ++mi)
#pragma unroll
      for (int ni = 0; ni < 4; ++ni) {
        int i = row0 + wr + mi * 16 + (lane & 15);
        int b = i >> 11, s = i & 2047;
#pragma unroll
        for (int r = 0; r < 4; ++r) {
          int j = col0 + wc + ni * 16 + (lane >> 4) * 4 + r;
          int h = j >> 6, hd = j & 63;
          o[((int64_t)(b * H_ + h) * HD_ + hd) * S_ + s] = f2bf(acc[mi][ni][r] + bias[j]);
        }
      }
  } else {
    float* o = (float*)out;
#pragma unroll
    for (int mi = 0; mi < 4; ++mi)
#pragma unroll
      for (int ni = 0; ni < 4; ++ni) {
        int j = col0 + wc + ni * 16 + (lane & 15);
        float bvv = bias[j];
#pragma unroll
        for (int r = 0; r < 4; ++r) {
          int i = row0 + wr + mi * 16 + (lane >> 4) * 4 + r;
          o[(int64_t)i * D_ + j] = acc[mi][ni][r] + bvv;
        }
      }
  }
}

// ---------------- flash attention (8-wave, 32x32 MFMA, MFMA-denominator) -------
// grid 512 (XCD-swizzled: 8 q-blocks x 64 bh), 8 waves x 32 q-rows = 256 q-rows
// per block share each staged 64-kv tile. Per wave per tile: 1 K + 1 V stage.
__global__ __launch_bounds__(512) void attn_kernel(
    const u16* __restrict__ Q, const u16* __restrict__ Kg,
    const u16* __restrict__ Vt, u16* __restrict__ AO) {
  __shared__ u16 Ks[2][64 * 64];   // swizzled [kv][hd]
  __shared__ u16 Vs[2][64 * 64];   // swizzled [hd][kv]
  const int tid = threadIdx.x;
  const int lane = tid & 63;
  const int l31 = lane & 31;
  const int hi = lane >> 5;
  const int wid = tid >> 6;        // 0..7
  const int orig = blockIdx.x;     // 512
  const int swz = (orig & 7) * 64 + (orig >> 3);
  const int bh = swz >> 3;
  const int qw = (swz & 7) * 256 + wid * 32;

  // Q as B-operand (32x32x16): col q = l31, k = ks*16 + hi*8 + j
  bf16x8 qf[4];
#pragma unroll
  for (int ks = 0; ks < 4; ++ks)
    qf[ks] = *reinterpret_cast<const bf16x8*>(
        Q + ((int64_t)bh * S_ + qw + l31) * HD_ + ks * 16 + hi * 8);

  bf16x8 ones8;
#pragma unroll
  for (int i = 0; i < 8; ++i) ones8[i] = (__bf16)1.0f;

  f32x16 o0 = {}, o1 = {}, ls = {};
  float mrow = -1e30f;

  const int srow = lane >> 3;
  const int cc = (lane & 7) ^ srow;

  // staging pointers: wave wid owns K row wid*8+srow and V row wid*8+srow
  const u16* kp = Kg + ((int64_t)bh * S_ + wid * 8 + srow) * HD_ + cc * 8;
  const u16* vp = Vt + ((int64_t)bh * HD_ + wid * 8 + srow) * S_ + cc * 8;

  // prologue: stage tile 0 -> buf 0
  gl2lds16(kp, (char*)Ks[0] + wid * 1024); kp += 64 * HD_;
  gl2lds16(vp, (char*)Vs[0] + wid * 1024); vp += 64;

  const int NT = S_ / 64;

#define TILE_STEP(T, CUR)                                                      \
  {                                                                            \
    asm volatile("s_waitcnt vmcnt(0)" ::: "memory");                           \
    __builtin_amdgcn_s_barrier();                                              \
    if ((T) + 1 < NT) {                                                        \
      gl2lds16(kp, (char*)Ks[(CUR) ^ 1] + wid * 1024);                         \
      gl2lds16(vp, (char*)Vs[(CUR) ^ 1] + wid * 1024);                         \
      kp += 64 * HD_; vp += 64;                                                \
    }                                                                          \
    f32x16 sc0 = {}, sc1 = {};                                                 \
    {                                                                          \
      const char* kbase = (const char*)Ks[CUR];                                \
      __builtin_amdgcn_s_setprio(1);                                           \
      _Pragma("unroll")                                                        \
      for (int ks = 0; ks < 4; ++ks) {                                         \
        int chunk = 2 * ks + hi;                                               \
        int r0 = l31, r1 = 32 + l31;                                           \
        bf16x8 k0 = *reinterpret_cast<const bf16x8*>(                          \
            kbase + r0 * 128 + ((chunk ^ (r0 & 7)) << 4));                     \
        bf16x8 k1 = *reinterpret_cast<const bf16x8*>(                          \
            kbase + r1 * 128 + ((chunk ^ (r1 & 7)) << 4));                     \
        sc0 = __builtin_amdgcn_mfma_f32_32x32x16_bf16(k0, qf[ks], sc0, 0, 0, 0); \
        sc1 = __builtin_amdgcn_mfma_f32_32x32x16_bf16(k1, qf[ks], sc1, 0, 0, 0); \
      }                                                                        \
      __builtin_amdgcn_s_setprio(0);                                           \
    }                                                                          \
    float a8[8];                                                               \
    _Pragma("unroll")                                                          \
    for (int i = 0; i < 8; ++i)                                                \
      a8[i] = fmaxf(fmaxf(fmaxf(sc0[2 * i], sc0[2 * i + 1]), sc1[2 * i]),      \
                    sc1[2 * i + 1]);                                           \
    float mx = fmaxf(fmaxf(fmaxf(fmaxf(a8[0], a8[1]), a8[2]), a8[3]),          \
                     fmaxf(fmaxf(fmaxf(a8[4], a8[5]), a8[6]), a8[7]));         \
    if (!__all((mx - mrow <= THR2) ? 1 : 0)) {                                 \
      float mxf = fmaxf(mx, __shfl_xor(mx, 32));                               \
      float mnew = fmaxf(mrow, mxf);                                           \
      float al = exp2_fast(mrow - mnew);                                       \
      mrow = mnew;                                                             \
      _Pragma("unroll")                                                        \
      for (int tt = 0; tt < 16; ++tt) {                                        \
        float at = __shfl(al, (tt & 3) + 8 * (tt >> 2) + 4 * hi);              \
        o0[tt] *= at; o1[tt] *= at; ls[tt] *= at;                              \
      }                                                                        \
    }                                                                          \
    _Pragma("unroll")                                                          \
    for (int tt = 0; tt < 16; ++tt) {                                          \
      sc0[tt] = exp2_fast(sc0[tt] - mrow);                                     \
      sc1[tt] = exp2_fast(sc1[tt] - mrow);                                     \
    }                                                                          \
    unsigned w0[4][2], w1[4][2];                                               \
    _Pragma("unroll")                                                          \
    for (int rr = 0; rr < 4; ++rr) {                                           \
      w0[rr][0] = packbf(sc0[4 * rr], sc0[4 * rr + 1]);                        \
      w0[rr][1] = packbf(sc0[4 * rr + 2], sc0[4 * rr + 3]);                    \
      w1[rr][0] = packbf(sc1[4 * rr], sc1[4 * rr + 1]);                        \
      w1[rr][1] = packbf(sc1[4 * rr + 2], sc1[4 * rr + 3]);                    \
    }                                                                          \
    unsigned rv0[2][2], rv1[2][2];                                             \
    _Pragma("unroll")                                                          \
    for (int c = 0; c < 2; ++c) {                                              \
      _Pragma("unroll")                                                        \
      for (int h2 = 0; h2 < 2; ++h2) {                                         \
        rv0[c][h2] = (unsigned)__shfl_xor(                                     \
            (int)(hi ? w0[2 * c][h2] : w0[2 * c + 1][h2]), 32);                \
        rv1[c][h2] = (unsigned)__shfl_xor(                                     \
            (int)(hi ? w1[2 * c][h2] : w1[2 * c + 1][h2]), 32);                \
      }                                                                        \
    }                                                                          \
    {                                                                          \
      const char* vbase = (const char*)Vs[CUR];                                \
      __builtin_amdgcn_s_setprio(1);                                           \
      _Pragma("unroll")                                                        \
      for (int kb = 0; kb < 4; ++kb) {                                         \
        const int c = kb & 1;                                                  \
        union { bf16x8 v; unsigned u[4]; } pu;                                 \
        if (kb < 2) {                                                          \
          pu.u[0] = hi ? rv0[c][0] : w0[2 * c][0];                             \
          pu.u[1] = hi ? rv0[c][1] : w0[2 * c][1];                             \
          pu.u[2] = hi ? w0[2 * c + 1][0] : rv0[c][0];                         \
          pu.u[3] = hi ? w0[2 * c + 1][1] : rv0[c][1];                         \
        } else {                                                               \
          pu.u[0] = hi ? rv1[c][0] : w1[2 * c][0];                             \
          pu.u[1] = hi ? rv1[c][1] : w1[2 * c][1];                             \
          pu.u[2] = hi ? w1[2 * c + 1][0] : rv1[c][0];                         \
          pu.u[3] = hi ? w1[2 * c + 1][1] : rv1[c][1];                         \
        }                                                                      \
        int chunk = 2 * kb + hi;                                               \
        int r0 = l31, r1 = 32 + l31;                                           \
        bf16x8 v0 = *reinterpret_cast<const bf16x8*>(                          \
            vbase + r0 * 128 + ((chunk ^ (r0 & 7)) << 4));                     \
        bf16x8 v1 = *reinterpret_cast<const bf16x8*>(                          \
            vbase + r1 * 128 + ((chunk ^ (r1 & 7)) << 4));                     \
        o0 = __builtin_amdgcn_mfma_f32_32x32x16_bf16(pu.v, v0, o0, 0, 0, 0);   \
        o1 = __builtin_amdgcn_mfma_f32_32x32x16_bf16(pu.v, v1, o1, 0, 0, 0);   \
        ls = __builtin_amdgcn_mfma_f32_32x32x16_bf16(pu.v, ones8, ls, 0, 0, 0);\
      }                                                                        \
      __builtin_amdgcn_s_setprio(0);                                           \
    }                                                                          \
  }

  for (int t = 0; t < NT; t += 2) {
    TILE_STEP(t, 0)
    TILE_STEP(t + 1, 1)
  }
#undef TILE_STEP

  // epilogue: elementwise normalize (ls has o0's exact layout), store
  const int b = bh >> 4, h = bh & 15;
#pragma unroll
  for (int tt = 0; tt < 16; ++tt) {
    int row = (tt & 3) + 8 * (tt >> 2) + 4 * hi;
    float inv = __builtin_amdgcn_rcpf(ls[tt]);
    int qr = qw + row;
    int64_t base = ((int64_t)(b * S_ + qr)) * D_ + h * HD_ + l31;
    AO[base] = f2bf(o0[tt] * inv);
    AO[base + 32] = f2bf(o1[tt] * inv);
  }
}

extern "C" void kernel_launch(void* const* d_in, const int* in_sizes, int n_in,
                              void* d_out, int out_size, void* d_ws, size_t ws_size,
                              hipStream_t stream) {
  const float* x  = (const float*)d_in[0];
  const float* wq = (const float*)d_in[1];
  const float* bq = (const float*)d_in[2];
  const float* wk = (const float*)d_in[3];
  const float* bk = (const float*)d_in[4];
  const float* wv = (const float*)d_in[5];
  const float* bv = (const float*)d_in[6];
  const float* wo = (const float*)d_in[7];
  const float* bo = (const float*)d_in[8];
  char* ws = (char*)d_ws;
  u16* xb  = (u16*)ws;
  u16* wqb = (u16*)(ws + (16ll << 20));
  u16* wkb = (u16*)(ws + (18ll << 20));
  u16* wvb = (u16*)(ws + (20ll << 20));
  u16* wob = (u16*)(ws + (22ll << 20));
  u16* q   = (u16*)(ws + (24ll << 20));
  u16* k   = (u16*)(ws + (40ll << 20));
  u16* vt  = (u16*)(ws + (56ll << 20));
  u16* ao  = xb;

  convert_kernel<<<12288, 256, 0, stream>>>(x, wq, wk, wv, wo, xb, wqb, wkb, wvb, wob);
  dim3 gg(D_ / 128, M_ / 128);  // natural map: XCD = col-block (weight panel resident)
  gemm_kernel<3><<<gg, 256, 0, stream>>>(xb, wqb, bq, q);   // Q, pre-scaled
  gemm_kernel<0><<<gg, 256, 0, stream>>>(xb, wkb, bk, k);
  gemm_kernel<1><<<gg, 256, 0, stream>>>(xb, wvb, bv, vt);  // V^T
  attn_kernel<<<512, 512, 0, stream>>>(q, k, vt, ao);
  gemm_kernel<2><<<gg, 256, 0, stream>>>(ao, wob, bo, (float*)d_out);
}

// Round 10
// 224.344 us; speedup vs baseline: 1.2727x; 1.0934x over previous
//
#include <hip/hip_runtime.h>
#include <stdint.h>

// B=4, S=2048, D=1024, H=16, HD=64. All inputs fp32.
// convert->bf16; Q(pre-scaled by 0.125*log2e),K in [B,H,S,HD]; V^T [B,H,HD,S];
// flash attention (8 waves x 64 q-rows = 512 q-rows/block share each staged KV
// tile; every LDS K/V fragment feeds 2 q-blocks' MFMAs; 32x32 MFMA, swapped
// QK^T, register softmax, MFMA denominator, shfl_xor(32) P swap, dbuf K/V,
// XCD swizzle) -> ao bf16; out = ao@wo^T+bo fp32.

#define B_ 4
#define S_ 2048
#define D_ 1024
#define H_ 16
#define HD_ 64
#define M_ (B_ * S_)

typedef __bf16 bf16x8 __attribute__((ext_vector_type(8)));
typedef float f32x4 __attribute__((ext_vector_type(4)));
typedef float f32x16 __attribute__((ext_vector_type(16)));
typedef unsigned short u16;

// 0.125 (1/sqrt(HD)) * log2(e): scores come out in log2 units
#define QSCALE 0.18033688011112042f
#define THR2 11.0f  // defer-max threshold in log2 units

__device__ __forceinline__ u16 f2bf(float f) {
  union { float f; unsigned u; } v; v.f = f;
  unsigned u = v.u;
  u += 0x7fff + ((u >> 16) & 1);
  return (u16)(u >> 16);
}

__device__ __forceinline__ float exp2_fast(float x) {
#if __has_builtin(__builtin_amdgcn_exp2f)
  return __builtin_amdgcn_exp2f(x);
#else
  return __expf(x * 0.69314718056f);
#endif
}

__device__ __forceinline__ unsigned packbf(float a, float b) {
  union { unsigned u; __bf16 h[2]; } v;
  v.h[0] = (__bf16)a; v.h[1] = (__bf16)b;
  return v.u;
}

__device__ __forceinline__ void gl2lds16(const void* g, void* l) {
  __builtin_amdgcn_global_load_lds(
      (const __attribute__((address_space(1))) unsigned int*)g,
      (__attribute__((address_space(3))) unsigned int*)l, 16, 0, 0);
}

// ---------------- convert fp32 -> bf16 ----------------
__global__ __launch_bounds__(256) void convert_kernel(
    const float* __restrict__ x, const float* __restrict__ wq,
    const float* __restrict__ wk, const float* __restrict__ wv,
    const float* __restrict__ wo, u16* __restrict__ xb, u16* __restrict__ wqb,
    u16* __restrict__ wkb, u16* __restrict__ wvb, u16* __restrict__ wob) {
  const int64_t NX = (int64_t)M_ * D_ / 4;
  const int64_t NW = (int64_t)D_ * D_ / 4;
  int64_t i = (int64_t)blockIdx.x * blockDim.x + threadIdx.x;
  const float* src; u16* dst; int64_t off;
  if (i < NX)              { src = x;  dst = xb;  off = i; }
  else if (i < NX + NW)    { src = wq; dst = wqb; off = i - NX; }
  else if (i < NX + 2*NW)  { src = wk; dst = wkb; off = i - NX - NW; }
  else if (i < NX + 3*NW)  { src = wv; dst = wvb; off = i - NX - 2*NW; }
  else                     { src = wo; dst = wob; off = i - NX - 3*NW; }
  float4 v = reinterpret_cast<const float4*>(src)[off];
  ushort4 o;
  o.x = f2bf(v.x); o.y = f2bf(v.y); o.z = f2bf(v.z); o.w = f2bf(v.w);
  reinterpret_cast<ushort4*>(dst)[off] = o;
}

// ---------------- bf16 MFMA GEMM: C = A(MxK) @ Bw(NxK)^T + bias ----------------
// MODE 0: bf16 out [B,H,S,HD] (K proj)   MODE 3: same, scaled by QSCALE (Q proj)
// MODE 1: swapped, bf16 out [B,H,HD,S] (V^T)   MODE 2: fp32 out [M,N] (final)
template <int MODE>
__global__ __launch_bounds__(256) void gemm_kernel(
    const u16* __restrict__ A, const u16* __restrict__ Bw,
    const float* __restrict__ bias, void* __restrict__ out) {
  __shared__ u16 As[128 * 64];
  __shared__ u16 Bs[128 * 64];
  const int tid = threadIdx.x;
  const int lane = tid & 63;
  const int wid = tid >> 6;
  const int row0 = blockIdx.y * 128;
  const int col0 = blockIdx.x * 128;
  const int wr = (wid >> 1) * 64;
  const int wc = (wid & 1) * 64;

  f32x4 acc[4][4] = {};
  const int srow = lane >> 3;
  const int cc = (lane & 7) ^ srow;

  for (int kt = 0; kt < D_; kt += 64) {
    __syncthreads();
    for (int t = 0; t < 4; ++t) {
      int r = (wid * 4 + t) * 8 + srow;
      gl2lds16(A + (int64_t)(row0 + r) * D_ + kt + cc * 8,
               (char*)As + (wid * 4 + t) * 1024);
      gl2lds16(Bw + (int64_t)(col0 + r) * D_ + kt + cc * 8,
               (char*)Bs + (wid * 4 + t) * 1024);
    }
    __syncthreads();

    bf16x8 af[4][2], bfr[4][2];
#pragma unroll
    for (int mi = 0; mi < 4; ++mi)
#pragma unroll
      for (int ks = 0; ks < 2; ++ks) {
        int c = ks * 4 + (lane >> 4);
        int ra = wr + mi * 16 + (lane & 15);
        af[mi][ks] = *reinterpret_cast<const bf16x8*>(
            (char*)As + ra * 128 + ((c ^ (ra & 7)) << 4));
        int rb = wc + mi * 16 + (lane & 15);
        bfr[mi][ks] = *reinterpret_cast<const bf16x8*>(
            (char*)Bs + rb * 128 + ((c ^ (rb & 7)) << 4));
      }
#pragma unroll
    for (int ks = 0; ks < 2; ++ks)
#pragma unroll
      for (int mi = 0; mi < 4; ++mi)
#pragma unroll
        for (int ni = 0; ni < 4; ++ni) {
          if (MODE == 1)
            acc[mi][ni] = __builtin_amdgcn_mfma_f32_16x16x32_bf16(
                bfr[ni][ks], af[mi][ks], acc[mi][ni], 0, 0, 0);
          else
            acc[mi][ni] = __builtin_amdgcn_mfma_f32_16x16x32_bf16(
                af[mi][ks], bfr[ni][ks], acc[mi][ni], 0, 0, 0);
        }
  }

  if (MODE == 0 || MODE == 3) {
    u16* o = (u16*)out;
#pragma unroll
    for (int mi = 0; mi < 4; ++mi)
#pragma unroll
      for (int ni = 0; ni < 4; ++ni) {
        int j = col0 + wc + ni * 16 + (lane & 15);
        float bvv = bias[j];
        int h = j >> 6, hd = j & 63;
#pragma unroll
        for (int r = 0; r < 4; ++r) {
          int i = row0 + wr + mi * 16 + (lane >> 4) * 4 + r;
          int b = i >> 11, s = i & 2047;
          float val = acc[mi][ni][r] + bvv;
          if (MODE == 3) val *= QSCALE;
          o[((int64_t)(b * H_ + h) * S_ + s) * HD_ + hd] = f2bf(val);
        }
      }
  } else if (MODE == 1) {
    u16* o = (u16*)out;
#pragma unroll
    for (int mi = 0; mi < 4; ++mi)
#pragma unroll
      for (int ni = 0; ni < 4; ++ni) {
        int i = row0 + wr + mi * 16 + (lane & 15);
        int b = i >> 11, s = i & 2047;
#pragma unroll
        for (int r = 0; r < 4; ++r) {
          int j = col0 + wc + ni * 16 + (lane >> 4) * 4 + r;
          int h = j >> 6, hd = j & 63;
          o[((int64_t)(b * H_ + h) * HD_ + hd) * S_ + s] = f2bf(acc[mi][ni][r] + bias[j]);
        }
      }
  } else {
    float* o = (float*)out;
#pragma unroll
    for (int mi = 0; mi < 4; ++mi)
#pragma unroll
      for (int ni = 0; ni < 4; ++ni) {
        int j = col0 + wc + ni * 16 + (lane & 15);
        float bvv = bias[j];
#pragma unroll
        for (int r = 0; r < 4; ++r) {
          int i = row0 + wr + mi * 16 + (lane >> 4) * 4 + r;
          o[(int64_t)i * D_ + j] = acc[mi][ni][r] + bvv;
        }
      }
  }
}

// ---------------- flash attention (8 waves x 64 q-rows, 32x32 MFMA) -----------
// grid 256 (XCD-swizzled: 4 q-segs x 64 bh), 512 threads. Wave owns 64 q-rows
// as two 32-row sub-blocks qb=0,1; each shared K/V LDS fragment feeds both.
__global__ __launch_bounds__(512, 2) void attn_kernel(
    const u16* __restrict__ Q, const u16* __restrict__ Kg,
    const u16* __restrict__ Vt, u16* __restrict__ AO) {
  __shared__ u16 Ks[2][64 * 64];   // swizzled [kv][hd]
  __shared__ u16 Vs[2][64 * 64];   // swizzled [hd][kv]
  const int tid = threadIdx.x;
  const int lane = tid & 63;
  const int l31 = lane & 31;
  const int hi = lane >> 5;
  const int wid = tid >> 6;        // 0..7
  const int orig = blockIdx.x;     // 256
  const int swz = (orig & 7) * 32 + (orig >> 3);
  const int bh = swz >> 2;
  const int qw = (swz & 3) * 512 + wid * 64;

  // Q as B-operand (32x32x16): qb sub-block q-col = qw + qb*32 + l31
  bf16x8 qf[2][4];
#pragma unroll
  for (int qb = 0; qb < 2; ++qb)
#pragma unroll
    for (int ks = 0; ks < 4; ++ks)
      qf[qb][ks] = *reinterpret_cast<const bf16x8*>(
          Q + ((int64_t)bh * S_ + qw + qb * 32 + l31) * HD_ + ks * 16 + hi * 8);

  bf16x8 ones8;
#pragma unroll
  for (int i = 0; i < 8; ++i) ones8[i] = (__bf16)1.0f;

  f32x16 o0[2] = {}, o1[2] = {}, ls[2] = {};
  float mrow[2] = {-1e30f, -1e30f};

  const int srow = lane >> 3;
  const int cc = (lane & 7) ^ srow;

  // staging pointers: wave wid owns K row wid*8+srow and V row wid*8+srow
  const u16* kp = Kg + ((int64_t)bh * S_ + wid * 8 + srow) * HD_ + cc * 8;
  const u16* vp = Vt + ((int64_t)bh * HD_ + wid * 8 + srow) * S_ + cc * 8;

  // prologue: stage tile 0 -> buf 0
  gl2lds16(kp, (char*)Ks[0] + wid * 1024); kp += 64 * HD_;
  gl2lds16(vp, (char*)Vs[0] + wid * 1024); vp += 64;

  const int NT = S_ / 64;

#define TILE_STEP(T, CUR)                                                      \
  {                                                                            \
    asm volatile("s_waitcnt vmcnt(0)" ::: "memory");                           \
    __builtin_amdgcn_s_barrier();                                              \
    if ((T) + 1 < NT) {                                                        \
      gl2lds16(kp, (char*)Ks[(CUR) ^ 1] + wid * 1024);                         \
      gl2lds16(vp, (char*)Vs[(CUR) ^ 1] + wid * 1024);                         \
      kp += 64 * HD_; vp += 64;                                                \
    }                                                                          \
    f32x16 sc0[2] = {{}, {}}, sc1[2] = {{}, {}};                               \
    {                                                                          \
      const char* kbase = (const char*)Ks[CUR];                                \
      __builtin_amdgcn_s_setprio(1);                                           \
      _Pragma("unroll")                                                        \
      for (int ks = 0; ks < 4; ++ks) {                                         \
        int chunk = 2 * ks + hi;                                               \
        int r0 = l31, r1 = 32 + l31;                                           \
        bf16x8 k0 = *reinterpret_cast<const bf16x8*>(                          \
            kbase + r0 * 128 + ((chunk ^ (r0 & 7)) << 4));                     \
        bf16x8 k1 = *reinterpret_cast<const bf16x8*>(                          \
            kbase + r1 * 128 + ((chunk ^ (r1 & 7)) << 4));                     \
        _Pragma("unroll")                                                      \
        for (int qb = 0; qb < 2; ++qb) {                                       \
          sc0[qb] = __builtin_amdgcn_mfma_f32_32x32x16_bf16(k0, qf[qb][ks],    \
                                                            sc0[qb], 0, 0, 0); \
          sc1[qb] = __builtin_amdgcn_mfma_f32_32x32x16_bf16(k1, qf[qb][ks],    \
                                                            sc1[qb], 0, 0, 0); \
        }                                                                      \
      }                                                                        \
      __builtin_amdgcn_s_setprio(0);                                           \
    }                                                                          \
    float mx[2];                                                               \
    _Pragma("unroll")                                                          \
    for (int qb = 0; qb < 2; ++qb) {                                           \
      float a8[8];                                                             \
      _Pragma("unroll")                                                        \
      for (int i = 0; i < 8; ++i)                                              \
        a8[i] = fmaxf(fmaxf(fmaxf(sc0[qb][2 * i], sc0[qb][2 * i + 1]),         \
                            sc1[qb][2 * i]), sc1[qb][2 * i + 1]);              \
      mx[qb] = fmaxf(fmaxf(fmaxf(fmaxf(a8[0], a8[1]), a8[2]), a8[3]),          \
                     fmaxf(fmaxf(fmaxf(a8[4], a8[5]), a8[6]), a8[7]));         \
    }                                                                          \
    int okd = (mx[0] - mrow[0] <= THR2 && mx[1] - mrow[1] <= THR2) ? 1 : 0;    \
    if (!__all(okd)) {                                                         \
      _Pragma("unroll")                                                        \
      for (int qb = 0; qb < 2; ++qb) {                                         \
        float mxf = fmaxf(mx[qb], __shfl_xor(mx[qb], 32));                     \
        float mnew = fmaxf(mrow[qb], mxf);                                     \
        float al = exp2_fast(mrow[qb] - mnew);                                 \
        mrow[qb] = mnew;                                                       \
        _Pragma("unroll")                                                      \
        for (int tt = 0; tt < 16; ++tt) {                                      \
          float at = __shfl(al, (tt & 3) + 8 * (tt >> 2) + 4 * hi);            \
          o0[qb][tt] *= at; o1[qb][tt] *= at; ls[qb][tt] *= at;                \
        }                                                                      \
      }                                                                        \
    }                                                                          \
    unsigned w[2][2][4][2], rv[2][2][2][2];                                    \
    _Pragma("unroll")                                                          \
    for (int qb = 0; qb < 2; ++qb) {                                           \
      _Pragma("unroll")                                                        \
      for (int tt = 0; tt < 16; ++tt) {                                        \
        sc0[qb][tt] = exp2_fast(sc0[qb][tt] - mrow[qb]);                       \
        sc1[qb][tt] = exp2_fast(sc1[qb][tt] - mrow[qb]);                       \
      }                                                                        \
      _Pragma("unroll")                                                        \
      for (int rr = 0; rr < 4; ++rr) {                                         \
        w[qb][0][rr][0] = packbf(sc0[qb][4 * rr], sc0[qb][4 * rr + 1]);        \
        w[qb][0][rr][1] = packbf(sc0[qb][4 * rr + 2], sc0[qb][4 * rr + 3]);    \
        w[qb][1][rr][0] = packbf(sc1[qb][4 * rr], sc1[qb][4 * rr + 1]);        \
        w[qb][1][rr][1] = packbf(sc1[qb][4 * rr + 2], sc1[qb][4 * rr + 3]);    \
      }                                                                        \
      _Pragma("unroll")                                                        \
      for (int n2 = 0; n2 < 2; ++n2) {                                         \
        _Pragma("unroll")                                                      \
        for (int c = 0; c < 2; ++c) {                                          \
          _Pragma("unroll")                                                    \
          for (int h2 = 0; h2 < 2; ++h2)                                       \
            rv[qb][n2][c][h2] = (unsigned)__shfl_xor(                          \
                (int)(hi ? w[qb][n2][2 * c][h2] : w[qb][n2][2 * c + 1][h2]),   \
                32);                                                           \
        }                                                                      \
      }                                                                        \
    }                                                                          \
    {                                                                          \
      const char* vbase = (const char*)Vs[CUR];                                \
      __builtin_amdgcn_s_setprio(1);                                           \
      _Pragma("unroll")                                                        \
      for (int kb = 0; kb < 4; ++kb) {                                         \
        const int c = kb & 1, n2 = kb >> 1;                                    \
        int chunk = 2 * kb + hi;                                               \
        int r0 = l31, r1 = 32 + l31;                                           \
        bf16x8 v0 = *reinterpret_cast<const bf16x8*>(                          \
            vbase + r0 * 128 + ((chunk ^ (r0 & 7)) << 4));                     \
        bf16x8 v1 = *reinterpret_cast<const bf16x8*>(                          \
            vbase + r1 * 128 + ((chunk ^ (r1 & 7)) << 4));                     \
        _Pragma("unroll")                                                      \
        for (int qb = 0; qb < 2; ++qb) {                                       \
          union { bf16x8 v; unsigned u[4]; } pu;                               \
          pu.u[0] = hi ? rv[qb][n2][c][0] : w[qb][n2][2 * c][0];               \
          pu.u[1] = hi ? rv[qb][n2][c][1] : w[qb][n2][2 * c][1];               \
          pu.u[2] = hi ? w[qb][n2][2 * c + 1][0] : rv[qb][n2][c][0];           \
          pu.u[3] = hi ? w[qb][n2][2 * c + 1][1] : rv[qb][n2][c][1];           \
          o0[qb] = __builtin_amdgcn_mfma_f32_32x32x16_bf16(pu.v, v0, o0[qb],   \
                                                           0, 0, 0);           \
          o1[qb] = __builtin_amdgcn_mfma_f32_32x32x16_bf16(pu.v, v1, o1[qb],   \
                                                           0, 0, 0);           \
          ls[qb] = __builtin_amdgcn_mfma_f32_32x32x16_bf16(pu.v, ones8,        \
                                                           ls[qb], 0, 0, 0);   \
        }                                                                      \
      }                                                                        \
      __builtin_amdgcn_s_setprio(0);                                           \
    }                                                                          \
  }

  for (int t = 0; t < NT; t += 2) {
    TILE_STEP(t, 0)
    TILE_STEP(t + 1, 1)
  }
#undef TILE_STEP

  // epilogue: elementwise normalize (ls has o0's exact layout), store
  const int b = bh >> 4, h = bh & 15;
#pragma unroll
  for (int qb = 0; qb < 2; ++qb)
#pragma unroll
    for (int tt = 0; tt < 16; ++tt) {
      int row = (tt & 3) + 8 * (tt >> 2) + 4 * hi;
      float inv = __builtin_amdgcn_rcpf(ls[qb][tt]);
      int qr = qw + qb * 32 + row;
      int64_t base = ((int64_t)(b * S_ + qr)) * D_ + h * HD_ + l31;
      AO[base] = f2bf(o0[qb][tt] * inv);
      AO[base + 32] = f2bf(o1[qb][tt] * inv);
    }
}

extern "C" void kernel_launch(void* const* d_in, const int* in_sizes, int n_in,
                              void* d_out, int out_size, void* d_ws, size_t ws_size,
                              hipStream_t stream) {
  const float* x  = (const float*)d_in[0];
  const float* wq = (const float*)d_in[1];
  const float* bq = (const float*)d_in[2];
  const float* wk = (const float*)d_in[3];
  const float* bk = (const float*)d_in[4];
  const float* wv = (const float*)d_in[5];
  const float* bv = (const float*)d_in[6];
  const float* wo = (const float*)d_in[7];
  const float* bo = (const float*)d_in[8];
  char* ws = (char*)d_ws;
  u16* xb  = (u16*)ws;
  u16* wqb = (u16*)(ws + (16ll << 20));
  u16* wkb = (u16*)(ws + (18ll << 20));
  u16* wvb = (u16*)(ws + (20ll << 20));
  u16* wob = (u16*)(ws + (22ll << 20));
  u16* q   = (u16*)(ws + (24ll << 20));
  u16* k   = (u16*)(ws + (40ll << 20));
  u16* vt  = (u16*)(ws + (56ll << 20));
  u16* ao  = xb;

  convert_kernel<<<12288, 256, 0, stream>>>(x, wq, wk, wv, wo, xb, wqb, wkb, wvb, wob);
  dim3 gg(D_ / 128, M_ / 128);  // natural map: XCD = col-block (weight panel resident)
  gemm_kernel<3><<<gg, 256, 0, stream>>>(xb, wqb, bq, q);   // Q, pre-scaled
  gemm_kernel<0><<<gg, 256, 0, stream>>>(xb, wkb, bk, k);
  gemm_kernel<1><<<gg, 256, 0, stream>>>(xb, wvb, bv, vt);  // V^T
  attn_kernel<<<256, 512, 0, stream>>>(q, k, vt, ao);
  gemm_kernel<2><<<gg, 256, 0, stream>>>(ao, wob, bo, (float*)d_out);
}

// Round 11
// 217.568 us; speedup vs baseline: 1.3123x; 1.0311x over previous
//
#include <hip/hip_runtime.h>
#include <stdint.h>

// B=4, S=2048, D=1024, H=16, HD=64. All inputs fp32.
// convert->bf16; Q(pre-scaled by 0.125*log2e),K in [B,H,S,HD]; V^T [B,H,HD,S];
// flash attention (8 waves x 64 q-rows; 32x32 MFMA swapped QK^T; K staged with
// swap23 row permutation so PV A-frags are lane-local packed registers — no
// cross-half exchange; register softmax, MFMA denominator, dbuf K/V, XCD
// swizzle) -> ao bf16; out = ao@wo^T+bo fp32.

#define B_ 4
#define S_ 2048
#define D_ 1024
#define H_ 16
#define HD_ 64
#define M_ (B_ * S_)

typedef __bf16 bf16x8 __attribute__((ext_vector_type(8)));
typedef float f32x4 __attribute__((ext_vector_type(4)));
typedef float f32x16 __attribute__((ext_vector_type(16)));
typedef unsigned short u16;
typedef union { bf16x8 v; unsigned u[4]; } bfu;

// 0.125 (1/sqrt(HD)) * log2(e): scores come out in log2 units
#define QSCALE 0.18033688011112042f
#define THR2 11.0f  // defer-max threshold in log2 units

__device__ __forceinline__ u16 f2bf(float f) {
  union { float f; unsigned u; } v; v.f = f;
  unsigned u = v.u;
  u += 0x7fff + ((u >> 16) & 1);
  return (u16)(u >> 16);
}

__device__ __forceinline__ float exp2_fast(float x) {
#if __has_builtin(__builtin_amdgcn_exp2f)
  return __builtin_amdgcn_exp2f(x);
#else
  return __expf(x * 0.69314718056f);
#endif
}

__device__ __forceinline__ unsigned packbf(float a, float b) {
  union { unsigned u; __bf16 h[2]; } v;
  v.h[0] = (__bf16)a; v.h[1] = (__bf16)b;
  return v.u;
}

__device__ __forceinline__ void gl2lds16(const void* g, void* l) {
  __builtin_amdgcn_global_load_lds(
      (const __attribute__((address_space(1))) unsigned int*)g,
      (__attribute__((address_space(3))) unsigned int*)l, 16, 0, 0);
}

// ---------------- convert fp32 -> bf16 ----------------
__global__ __launch_bounds__(256) void convert_kernel(
    const float* __restrict__ x, const float* __restrict__ wq,
    const float* __restrict__ wk, const float* __restrict__ wv,
    const float* __restrict__ wo, u16* __restrict__ xb, u16* __restrict__ wqb,
    u16* __restrict__ wkb, u16* __restrict__ wvb, u16* __restrict__ wob) {
  const int64_t NX = (int64_t)M_ * D_ / 4;
  const int64_t NW = (int64_t)D_ * D_ / 4;
  int64_t i = (int64_t)blockIdx.x * blockDim.x + threadIdx.x;
  const float* src; u16* dst; int64_t off;
  if (i < NX)              { src = x;  dst = xb;  off = i; }
  else if (i < NX + NW)    { src = wq; dst = wqb; off = i - NX; }
  else if (i < NX + 2*NW)  { src = wk; dst = wkb; off = i - NX - NW; }
  else if (i < NX + 3*NW)  { src = wv; dst = wvb; off = i - NX - 2*NW; }
  else                     { src = wo; dst = wob; off = i - NX - 3*NW; }
  float4 v = reinterpret_cast<const float4*>(src)[off];
  ushort4 o;
  o.x = f2bf(v.x); o.y = f2bf(v.y); o.z = f2bf(v.z); o.w = f2bf(v.w);
  reinterpret_cast<ushort4*>(dst)[off] = o;
}

// ---------------- bf16 MFMA GEMM: C = A(MxK) @ Bw(NxK)^T + bias ----------------
// MODE 0: bf16 out [B,H,S,HD] (K proj)   MODE 3: same, scaled by QSCALE (Q proj)
// MODE 1: swapped, bf16 out [B,H,HD,S] (V^T)   MODE 2: fp32 out [M,N] (final)
template <int MODE>
__global__ __launch_bounds__(256) void gemm_kernel(
    const u16* __restrict__ A, const u16* __restrict__ Bw,
    const float* __restrict__ bias, void* __restrict__ out) {
  __shared__ u16 As[128 * 64];
  __shared__ u16 Bs[128 * 64];
  const int tid = threadIdx.x;
  const int lane = tid & 63;
  const int wid = tid >> 6;
  const int row0 = blockIdx.y * 128;
  const int col0 = blockIdx.x * 128;
  const int wr = (wid >> 1) * 64;
  const int wc = (wid & 1) * 64;

  f32x4 acc[4][4] = {};
  const int srow = lane >> 3;
  const int cc = (lane & 7) ^ srow;

  for (int kt = 0; kt < D_; kt += 64) {
    __syncthreads();
    for (int t = 0; t < 4; ++t) {
      int r = (wid * 4 + t) * 8 + srow;
      gl2lds16(A + (int64_t)(row0 + r) * D_ + kt + cc * 8,
               (char*)As + (wid * 4 + t) * 1024);
      gl2lds16(Bw + (int64_t)(col0 + r) * D_ + kt + cc * 8,
               (char*)Bs + (wid * 4 + t) * 1024);
    }
    __syncthreads();

    bf16x8 af[4][2], bfr[4][2];
#pragma unroll
    for (int mi = 0; mi < 4; ++mi)
#pragma unroll
      for (int ks = 0; ks < 2; ++ks) {
        int c = ks * 4 + (lane >> 4);
        int ra = wr + mi * 16 + (lane & 15);
        af[mi][ks] = *reinterpret_cast<const bf16x8*>(
            (char*)As + ra * 128 + ((c ^ (ra & 7)) << 4));
        int rb = wc + mi * 16 + (lane & 15);
        bfr[mi][ks] = *reinterpret_cast<const bf16x8*>(
            (char*)Bs + rb * 128 + ((c ^ (rb & 7)) << 4));
      }
#pragma unroll
    for (int ks = 0; ks < 2; ++ks)
#pragma unroll
      for (int mi = 0; mi < 4; ++mi)
#pragma unroll
        for (int ni = 0; ni < 4; ++ni) {
          if (MODE == 1)
            acc[mi][ni] = __builtin_amdgcn_mfma_f32_16x16x32_bf16(
                bfr[ni][ks], af[mi][ks], acc[mi][ni], 0, 0, 0);
          else
            acc[mi][ni] = __builtin_amdgcn_mfma_f32_16x16x32_bf16(
                af[mi][ks], bfr[ni][ks], acc[mi][ni], 0, 0, 0);
        }
  }

  if (MODE == 0 || MODE == 3) {
    u16* o = (u16*)out;
#pragma unroll
    for (int mi = 0; mi < 4; ++mi)
#pragma unroll
      for (int ni = 0; ni < 4; ++ni) {
        int j = col0 + wc + ni * 16 + (lane & 15);
        float bvv = bias[j];
        int h = j >> 6, hd = j & 63;
#pragma unroll
        for (int r = 0; r < 4; ++r) {
          int i = row0 + wr + mi * 16 + (lane >> 4) * 4 + r;
          int b = i >> 11, s = i & 2047;
          float val = acc[mi][ni][r] + bvv;
          if (MODE == 3) val *= QSCALE;
          o[((int64_t)(b * H_ + h) * S_ + s) * HD_ + hd] = f2bf(val);
        }
      }
  } else if (MODE == 1) {
    u16* o = (u16*)out;
#pragma unroll
    for (int mi = 0; mi < 4; ++mi)
#pragma unroll
      for (int ni = 0; ni < 4; ++ni) {
        int i = row0 + wr + mi * 16 + (lane & 15);
        int b = i >> 11, s = i & 2047;
#pragma unroll
        for (int r = 0; r < 4; ++r) {
          int j = col0 + wc + ni * 16 + (lane >> 4) * 4 + r;
          int h = j >> 6, hd = j & 63;
          o[((int64_t)(b * H_ + h) * HD_ + hd) * S_ + s] = f2bf(acc[mi][ni][r] + bias[j]);
        }
      }
  } else {
    float* o = (float*)out;
#pragma unroll
    for (int mi = 0; mi < 4; ++mi)
#pragma unroll
      for (int ni = 0; ni < 4; ++ni) {
        int j = col0 + wc + ni * 16 + (lane & 15);
        float bvv = bias[j];
#pragma unroll
        for (int r = 0; r < 4; ++r) {
          int i = row0 + wr + mi * 16 + (lane >> 4) * 4 + r;
          o[(int64_t)i * D_ + j] = acc[mi][ni][r] + bvv;
        }
      }
  }
}

// ---------------- flash attention (8 waves x 64 q-rows, permuted-K staging) ----
// grid 256 (XCD-swizzled). K staged with swap23 row permutation: LDS row r holds
// global kv row swap23(r) -> lane's C regs are kv-contiguous per 8-run, so PV
// A-frags = own packed registers (no shuffles/selects).
__global__ __launch_bounds__(512, 2) void attn_kernel(
    const u16* __restrict__ Q, const u16* __restrict__ Kg,
    const u16* __restrict__ Vt, u16* __restrict__ AO) {
  __shared__ u16 Ks[2][64 * 64];   // swizzled [kv][hd], rows kv-permuted by swap23
  __shared__ u16 Vs[2][64 * 64];   // swizzled [hd][kv], true kv order
  const int tid = threadIdx.x;
  const int lane = tid & 63;
  const int l31 = lane & 31;
  const int hi = lane >> 5;
  const int wid = tid >> 6;        // 0..7
  const int orig = blockIdx.x;     // 256
  const int swz = (orig & 7) * 32 + (orig >> 3);
  const int bh = swz >> 2;
  const int qw = (swz & 3) * 512 + wid * 64;

  // Q as B-operand (32x32x16): qb sub-block q-col = qw + qb*32 + l31
  bf16x8 qf[2][4];
#pragma unroll
  for (int qb = 0; qb < 2; ++qb)
#pragma unroll
    for (int ks = 0; ks < 4; ++ks)
      qf[qb][ks] = *reinterpret_cast<const bf16x8*>(
          Q + ((int64_t)bh * S_ + qw + qb * 32 + l31) * HD_ + ks * 16 + hi * 8);

  bf16x8 ones8;
#pragma unroll
  for (int i = 0; i < 8; ++i) ones8[i] = (__bf16)1.0f;

  f32x16 o0[2] = {}, o1[2] = {}, ls[2] = {};
  float mrow[2] = {-1e30f, -1e30f};

  const int srow = lane >> 3;
  const int cc = (lane & 7) ^ srow;

  // staging: LDS row lr = wid*8+srow holds global K row swap23(lr); V linear.
  const int lr = wid * 8 + srow;
  const int sr = (lr & ~12) | ((lr & 4) << 1) | ((lr & 8) >> 1);  // swap bits 2,3
  const u16* kp = Kg + ((int64_t)bh * S_ + sr) * HD_ + cc * 8;
  const u16* vp = Vt + ((int64_t)bh * HD_ + lr) * S_ + cc * 8;

  // prologue: stage tile 0 -> buf 0
  gl2lds16(kp, (char*)Ks[0] + wid * 1024); kp += 64 * HD_;
  gl2lds16(vp, (char*)Vs[0] + wid * 1024); vp += 64;

  const int NT = S_ / 64;

#define TILE_STEP(T, CUR)                                                      \
  {                                                                            \
    asm volatile("s_waitcnt vmcnt(0)" ::: "memory");                           \
    __builtin_amdgcn_s_barrier();                                              \
    if ((T) + 1 < NT) {                                                        \
      gl2lds16(kp, (char*)Ks[(CUR) ^ 1] + wid * 1024);                         \
      gl2lds16(vp, (char*)Vs[(CUR) ^ 1] + wid * 1024);                         \
      kp += 64 * HD_; vp += 64;                                                \
    }                                                                          \
    f32x16 sc0[2] = {{}, {}}, sc1[2] = {{}, {}};                               \
    {                                                                          \
      const char* kbase = (const char*)Ks[CUR];                                \
      __builtin_amdgcn_s_setprio(1);                                           \
      _Pragma("unroll")                                                        \
      for (int ks = 0; ks < 4; ++ks) {                                         \
        int chunk = 2 * ks + hi;                                               \
        int r0 = l31, r1 = 32 + l31;                                           \
        bf16x8 k0 = *reinterpret_cast<const bf16x8*>(                          \
            kbase + r0 * 128 + ((chunk ^ (r0 & 7)) << 4));                     \
        bf16x8 k1 = *reinterpret_cast<const bf16x8*>(                          \
            kbase + r1 * 128 + ((chunk ^ (r1 & 7)) << 4));                     \
        _Pragma("unroll")                                                      \
        for (int qb = 0; qb < 2; ++qb) {                                       \
          sc0[qb] = __builtin_amdgcn_mfma_f32_32x32x16_bf16(k0, qf[qb][ks],    \
                                                            sc0[qb], 0, 0, 0); \
          sc1[qb] = __builtin_amdgcn_mfma_f32_32x32x16_bf16(k1, qf[qb][ks],    \
                                                            sc1[qb], 0, 0, 0); \
        }                                                                      \
      }                                                                        \
      __builtin_amdgcn_s_setprio(0);                                           \
    }                                                                          \
    float mx[2];                                                               \
    _Pragma("unroll")                                                          \
    for (int qb = 0; qb < 2; ++qb) {                                           \
      float a8[8];                                                             \
      _Pragma("unroll")                                                        \
      for (int i = 0; i < 8; ++i)                                              \
        a8[i] = fmaxf(fmaxf(fmaxf(sc0[qb][2 * i], sc0[qb][2 * i + 1]),         \
                            sc1[qb][2 * i]), sc1[qb][2 * i + 1]);              \
      mx[qb] = fmaxf(fmaxf(fmaxf(fmaxf(a8[0], a8[1]), a8[2]), a8[3]),          \
                     fmaxf(fmaxf(fmaxf(a8[4], a8[5]), a8[6]), a8[7]));         \
    }                                                                          \
    int okd = (mx[0] - mrow[0] <= THR2 && mx[1] - mrow[1] <= THR2) ? 1 : 0;    \
    if (!__all(okd)) {                                                         \
      _Pragma("unroll")                                                        \
      for (int qb = 0; qb < 2; ++qb) {                                         \
        float mxf = fmaxf(mx[qb], __shfl_xor(mx[qb], 32));                     \
        float mnew = fmaxf(mrow[qb], mxf);                                     \
        float al = exp2_fast(mrow[qb] - mnew);                                 \
        mrow[qb] = mnew;                                                       \
        _Pragma("unroll")                                                      \
        for (int tt = 0; tt < 16; ++tt) {                                      \
          float at = __shfl(al, (tt & 3) + 8 * (tt >> 2) + 4 * hi);            \
          o0[qb][tt] *= at; o1[qb][tt] *= at; ls[qb][tt] *= at;                \
        }                                                                      \
      }                                                                        \
    }                                                                          \
    bfu pa[2][4];                                                              \
    _Pragma("unroll")                                                          \
    for (int qb = 0; qb < 2; ++qb) {                                           \
      _Pragma("unroll")                                                        \
      for (int tt = 0; tt < 16; ++tt) {                                        \
        sc0[qb][tt] = exp2_fast(sc0[qb][tt] - mrow[qb]);                       \
        sc1[qb][tt] = exp2_fast(sc1[qb][tt] - mrow[qb]);                       \
      }                                                                        \
      _Pragma("unroll")                                                        \
      for (int m = 0; m < 4; ++m) {                                            \
        pa[qb][0].u[m] = packbf(sc0[qb][2 * m], sc0[qb][2 * m + 1]);           \
        pa[qb][1].u[m] = packbf(sc0[qb][8 + 2 * m], sc0[qb][9 + 2 * m]);       \
        pa[qb][2].u[m] = packbf(sc1[qb][2 * m], sc1[qb][2 * m + 1]);           \
        pa[qb][3].u[m] = packbf(sc1[qb][8 + 2 * m], sc1[qb][9 + 2 * m]);       \
      }                                                                        \
    }                                                                          \
    {                                                                          \
      const char* vbase = (const char*)Vs[CUR];                                \
      __builtin_amdgcn_s_setprio(1);                                           \
      _Pragma("unroll")                                                        \
      for (int kb = 0; kb < 4; ++kb) {                                         \
        int chunk = 2 * kb + hi;                                               \
        int r0 = l31, r1 = 32 + l31;                                           \
        bf16x8 v0 = *reinterpret_cast<const bf16x8*>(                          \
            vbase + r0 * 128 + ((chunk ^ (r0 & 7)) << 4));                     \
        bf16x8 v1 = *reinterpret_cast<const bf16x8*>(                          \
            vbase + r1 * 128 + ((chunk ^ (r1 & 7)) << 4));                     \
        _Pragma("unroll")                                                      \
        for (int qb = 0; qb < 2; ++qb) {                                       \
          o0[qb] = __builtin_amdgcn_mfma_f32_32x32x16_bf16(pa[qb][kb].v, v0,   \
                                                           o0[qb], 0, 0, 0);   \
          o1[qb] = __builtin_amdgcn_mfma_f32_32x32x16_bf16(pa[qb][kb].v, v1,   \
                                                           o1[qb], 0, 0, 0);   \
          ls[qb] = __builtin_amdgcn_mfma_f32_32x32x16_bf16(pa[qb][kb].v,       \
                                                           ones8, ls[qb],      \
                                                           0, 0, 0);           \
        }                                                                      \
      }                                                                        \
      __builtin_amdgcn_s_setprio(0);                                           \
    }                                                                          \
  }

  for (int t = 0; t < NT; t += 2) {
    TILE_STEP(t, 0)
    TILE_STEP(t + 1, 1)
  }
#undef TILE_STEP

  // epilogue: elementwise normalize (ls has o0's exact layout), store
  const int b = bh >> 4, h = bh & 15;
#pragma unroll
  for (int qb = 0; qb < 2; ++qb)
#pragma unroll
    for (int tt = 0; tt < 16; ++tt) {
      int row = (tt & 3) + 8 * (tt >> 2) + 4 * hi;
      float inv = __builtin_amdgcn_rcpf(ls[qb][tt]);
      int qr = qw + qb * 32 + row;
      int64_t base = ((int64_t)(b * S_ + qr)) * D_ + h * HD_ + l31;
      AO[base] = f2bf(o0[qb][tt] * inv);
      AO[base + 32] = f2bf(o1[qb][tt] * inv);
    }
}

extern "C" void kernel_launch(void* const* d_in, const int* in_sizes, int n_in,
                              void* d_out, int out_size, void* d_ws, size_t ws_size,
                              hipStream_t stream) {
  const float* x  = (const float*)d_in[0];
  const float* wq = (const float*)d_in[1];
  const float* bq = (const float*)d_in[2];
  const float* wk = (const float*)d_in[3];
  const float* bk = (const float*)d_in[4];
  const float* wv = (const float*)d_in[5];
  const float* bv = (const float*)d_in[6];
  const float* wo = (const float*)d_in[7];
  const float* bo = (const float*)d_in[8];
  char* ws = (char*)d_ws;
  u16* xb  = (u16*)ws;
  u16* wqb = (u16*)(ws + (16ll << 20));
  u16* wkb = (u16*)(ws + (18ll << 20));
  u16* wvb = (u16*)(ws + (20ll << 20));
  u16* wob = (u16*)(ws + (22ll << 20));
  u16* q   = (u16*)(ws + (24ll << 20));
  u16* k   = (u16*)(ws + (40ll << 20));
  u16* vt  = (u16*)(ws + (56ll << 20));
  u16* ao  = xb;

  convert_kernel<<<12288, 256, 0, stream>>>(x, wq, wk, wv, wo, xb, wqb, wkb, wvb, wob);
  dim3 gg(D_ / 128, M_ / 128);  // natural map: XCD = col-block (weight panel resident)
  gemm_kernel<3><<<gg, 256, 0, stream>>>(xb, wqb, bq, q);   // Q, pre-scaled
  gemm_kernel<0><<<gg, 256, 0, stream>>>(xb, wkb, bk, k);
  gemm_kernel<1><<<gg, 256, 0, stream>>>(xb, wvb, bv, vt);  // V^T
  attn_kernel<<<256, 512, 0, stream>>>(q, k, vt, ao);
  gemm_kernel<2><<<gg, 256, 0, stream>>>(ao, wob, bo, (float*)d_out);
}